// Round 13
// baseline (276.588 us; speedup 1.0000x reference)
//
#include <hip/hip_runtime.h>

#define HW 1024
#define CD 512

typedef __bf16 bf16x8 __attribute__((ext_vector_type(8)));
typedef float f32x4 __attribute__((ext_vector_type(4)));

__device__ __forceinline__ unsigned short f2bf(float f) {
    unsigned int u = __float_as_uint(f);
    u += 0x7fff + ((u >> 16) & 1);   // RNE
    return (unsigned short)(u >> 16);
}
__device__ __forceinline__ float bf2f(unsigned short h) {
    return __uint_as_float((unsigned)h << 16);
}

#define AS1(p) ((__attribute__((address_space(1))) void*)(p))
#define AS3(p) ((__attribute__((address_space(3))) void*)(p))
#define GLD16(gp, lp) __builtin_amdgcn_global_load_lds(AS1(gp), AS3(lp), 16, 0, 0)

// ---------------- GroupNorm stats: one block per (b,g)
__global__ __launch_bounds__(256)
void gn_stats(const float* __restrict__ x, float* __restrict__ mean, float* __restrict__ rstd) {
    int bg = blockIdx.x;
    const float4* p4 = (const float4*)(x + (size_t)bg * 65536);
    int tid = threadIdx.x;
    float s = 0.f, ss = 0.f;
#pragma unroll 8
    for (int it = 0; it < 64; ++it) {
        float4 v = p4[tid + it * 256];
        s  += v.x + v.y + v.z + v.w;
        ss += v.x * v.x + v.y * v.y + v.z * v.z + v.w * v.w;
    }
#pragma unroll
    for (int d = 32; d > 0; d >>= 1) { s += __shfl_down(s, d); ss += __shfl_down(ss, d); }
    __shared__ float ls[4], lss[4];
    if ((tid & 63) == 0) { ls[tid >> 6] = s; lss[tid >> 6] = ss; }
    __syncthreads();
    if (tid == 0) {
        float S = ls[0] + ls[1] + ls[2] + ls[3];
        float SS = lss[0] + lss[1] + lss[2] + lss[3];
        float m = S * (1.f / 65536.f);
        float v = SS * (1.f / 65536.f) - m * m;
        mean[bg] = m;
        rstd[bg] = rsqrtf(v + 1e-5f);
    }
}

// ---------------- normalize + transpose: x[b,c,hw] f32 -> xnT[b,hw,c] bf16 (pad 67)
__global__ __launch_bounds__(256)
void gn_norm_t(const float* __restrict__ x, const float* __restrict__ mean, const float* __restrict__ rstd,
               const float* __restrict__ gamma, const float* __restrict__ beta,
               unsigned short* __restrict__ xnT) {
    __shared__ unsigned short tile[64][67];
    int i0 = blockIdx.x * 64, c0 = blockIdx.y * 64, b = blockIdx.z;
    float m = mean[b * 8 + blockIdx.y];
    float r = rstd[b * 8 + blockIdx.y];
    int tid = threadIdx.x;
    int tr = tid >> 4, tc = (tid & 15) * 4;
    const float* xb = x + ((size_t)b * CD + c0) * HW + i0;
#pragma unroll
    for (int p = 0; p < 4; ++p) {
        int c = tr + p * 16;
        float g = gamma[c0 + c] * r;
        float bb = beta[c0 + c] - m * g;
        float4 v = *(const float4*)(xb + (size_t)c * HW + tc);
        tile[c][tc + 0] = f2bf(v.x * g + bb);
        tile[c][tc + 1] = f2bf(v.y * g + bb);
        tile[c][tc + 2] = f2bf(v.z * g + bb);
        tile[c][tc + 3] = f2bf(v.w * g + bb);
    }
    __syncthreads();
    unsigned short* ob = xnT + ((size_t)b * HW + i0) * CD + c0;
#pragma unroll
    for (int p = 0; p < 4; ++p) {
        int ir = tr + p * 16;
        ushort4 u;
        u.x = tile[tc + 0][ir];
        u.y = tile[tc + 1][ir];
        u.z = tile[tc + 2][ir];
        u.w = tile[tc + 3][ir];
        *(ushort4*)(ob + (size_t)ir * CD + tc) = u;
    }
}

// ---------------- transpose + cvt x3: qkv_w row-blocks -> bf16 transposed (pad 67)
__global__ __launch_bounds__(256)
void tpose3_bf16(const float* __restrict__ qkv_w, unsigned short* __restrict__ dst0) {
    __shared__ unsigned short tile[64][67];
    const int zmap[3] = {0, 2, 1};
    const float* src = qkv_w + (size_t)blockIdx.z * CD * CD;
    unsigned short* dst = dst0 + (size_t)zmap[blockIdx.z] * CD * CD;
    int i0 = blockIdx.x * 64, c0 = blockIdx.y * 64;
    int tid = threadIdx.x;
    int tr = tid >> 4, tc = (tid & 15) * 4;
#pragma unroll
    for (int p = 0; p < 4; ++p) {
        int r = tr + p * 16;
        float4 v = *(const float4*)(src + (size_t)(i0 + r) * CD + c0 + tc);
        tile[r][tc + 0] = f2bf(v.x);
        tile[r][tc + 1] = f2bf(v.y);
        tile[r][tc + 2] = f2bf(v.z);
        tile[r][tc + 3] = f2bf(v.w);
    }
    __syncthreads();
#pragma unroll
    for (int p = 0; p < 4; ++p) {
        int ir = tr + p * 16;
        ushort4 u;
        u.x = tile[tc + 0][ir];
        u.y = tile[tc + 1][ir];
        u.z = tile[tc + 2][ir];
        u.w = tile[tc + 3][ir];
        *(ushort4*)(dst + (size_t)(c0 + ir) * CD + i0 + tc) = u;
    }
}

// ---------------- f32 -> bf16 convert
__global__ __launch_bounds__(256)
void cvt_bf16(const float* __restrict__ src, unsigned short* __restrict__ dst) {
    int i = blockIdx.x * 256 + threadIdx.x;
    float4 v = ((const float4*)src)[i];
    ushort4 u;
    u.x = f2bf(v.x); u.y = f2bf(v.y); u.z = f2bf(v.z); u.w = f2bf(v.w);
    ((ushort4*)dst)[i] = u;
}

// ---------------- g[d] = sum_o wk[o][d] * bq[o]
__global__ __launch_bounds__(256)
void gvec_kernel(const float* __restrict__ wk, const float* __restrict__ bq,
                 float* __restrict__ g) {
    __shared__ float red[4][64];
    int d = blockIdx.x * 64 + (threadIdx.x & 63);
    int os = threadIdx.x >> 6;
    float acc = 0.f;
    for (int o = os * 128; o < os * 128 + 128; ++o)
        acc += wk[(size_t)o * CD + d] * bq[o];
    red[os][threadIdx.x & 63] = acc;
    __syncthreads();
    if (threadIdx.x < 64)
        g[blockIdx.x * 64 + threadIdx.x] = red[0][threadIdx.x] + red[1][threadIdx.x] +
                                           red[2][threadIdx.x] + red[3][threadIdx.x];
}

// ---------------- bias2[o] = sum_t out_w[o][t] * bv[t]
__global__ __launch_bounds__(256)
void bias2_kernel(const float* __restrict__ out_w, const float* __restrict__ bv,
                  float* __restrict__ bias2) {
    int wid = threadIdx.x >> 6, lane = threadIdx.x & 63;
    int o = blockIdx.x * 4 + wid;
    float acc = 0.f;
#pragma unroll
    for (int t = 0; t < 512; t += 64)
        acc += out_w[(size_t)o * CD + t + lane] * bv[t + lane];
#pragma unroll
    for (int d = 32; d > 0; d >>= 1) acc += __shfl_down(acc, d);
    if (lane == 0) bias2[o] = acc;
}

// ---------------- 128x128 GEMM (proven) — kept for the small weight-pair GEMM
__global__ __launch_bounds__(256, 2)
void gemm_w(const unsigned short* __restrict__ A, const unsigned short* __restrict__ B,
            unsigned short* __restrict__ C, int K, long long sA, long long sB, long long sC) {
    unsigned nx = gridDim.x, ny = gridDim.y;
    unsigned lin = blockIdx.x + nx * (blockIdx.y + ny * blockIdx.z);
    unsigned nwg = nx * ny * gridDim.z;
    unsigned work = (lin & 7) * (nwg >> 3) + (lin >> 3);
    unsigned bx = work % nx; work /= nx;
    unsigned by = work % ny;
    unsigned bz = work / ny;

    A += (size_t)bz * sA;
    B += (size_t)bz * sB;
    int m0 = by * 128, n0 = bx * 128;

    __shared__ unsigned short lA[128 * 64];
    __shared__ unsigned short lB[128 * 64];

    int tid = threadIdx.x, lane = tid & 63;
    int wr = (tid >> 6) >> 1, wc = (tid >> 6) & 1;

    f32x4 acc[4][4] = {};
    int strow[4], stcol[4];
#pragma unroll
    for (int s = 0; s < 4; ++s) {
        int row = (s * 256 + tid) >> 3;
        int g = (tid & 7) ^ (row & 7);
        strow[s] = row;
        stcol[s] = g * 8;
    }

    for (int k0 = 0; k0 < K; k0 += 64) {
#pragma unroll
        for (int s = 0; s < 4; ++s) {
            GLD16(A + (size_t)(m0 + strow[s]) * K + k0 + stcol[s], lA + (size_t)(s * 256 + tid) * 8);
            GLD16(B + (size_t)(n0 + strow[s]) * K + k0 + stcol[s], lB + (size_t)(s * 256 + tid) * 8);
        }
        __syncthreads();
#pragma unroll
        for (int kk = 0; kk < 64; kk += 32) {
            bf16x8 af[4], bfr[4];
#pragma unroll
            for (int m = 0; m < 4; ++m) {
                int row = wr * 64 + m * 16 + (lane & 15);
                int off = (row * 128 + (kk + (lane >> 4) * 8) * 2) ^ ((row & 7) << 4);
                af[m] = *(const bf16x8*)((const char*)lA + off);
            }
#pragma unroll
            for (int n = 0; n < 4; ++n) {
                int row = wc * 64 + n * 16 + (lane & 15);
                int off = (row * 128 + (kk + (lane >> 4) * 8) * 2) ^ ((row & 7) << 4);
                bfr[n] = *(const bf16x8*)((const char*)lB + off);
            }
#pragma unroll
            for (int m = 0; m < 4; ++m)
#pragma unroll
                for (int n = 0; n < 4; ++n)
                    acc[m][n] = __builtin_amdgcn_mfma_f32_16x16x32_bf16(af[m], bfr[n], acc[m][n], 0, 0, 0);
        }
        __syncthreads();
    }

    int rl = (lane >> 4) * 4;
    int cl = lane & 15;
    unsigned short* Cb = C + (size_t)bz * sC;
#pragma unroll
    for (int m = 0; m < 4; ++m)
#pragma unroll
        for (int n = 0; n < 4; ++n) {
            int gm = m0 + wr * 64 + m * 16 + rl;
            int gn = n0 + wc * 64 + n * 16 + cl;
#pragma unroll
            for (int rg = 0; rg < 4; ++rg)
                Cb[(size_t)(gm + rg) * 512 + gn] = f2bf(acc[m][n][rg]);
        }
}

// ================= 256x128-tile single-buffered GEMM, 512 thr (8 waves of 64x64) ======
// 48 KB LDS -> 2 blocks/CU. Same per-wave maps as the 128^2 kernel.
// EPI 0: bf16 + bias[col] | 1: bf16 + bias[row]
template<int EPI>
__global__ __launch_bounds__(512, 4)
void gemm_bt2(const unsigned short* __restrict__ A, const unsigned short* __restrict__ B,
              unsigned short* __restrict__ C, const float* __restrict__ bias,
              int M, int N, int K, long long sA, long long sB, long long sC) {
    unsigned nx = gridDim.x, ny = gridDim.y;
    unsigned lin = blockIdx.x + nx * (blockIdx.y + ny * blockIdx.z);
    unsigned nwg = nx * ny * gridDim.z;
    unsigned work = (lin & 7) * (nwg >> 3) + (lin >> 3);
    unsigned bx = work % nx; work /= nx;
    unsigned by = work % ny;
    unsigned bz = work / ny;

    A += (size_t)bz * sA;
    B += (size_t)bz * sB;
    int m0 = by * 256, n0 = bx * 128;

    __shared__ unsigned short lA[256 * 64];
    __shared__ unsigned short lB[128 * 64];

    int tid = threadIdx.x, lane = tid & 63;
    int wid = tid >> 6;
    int wr = wid >> 1, wc = wid & 1;     // 4M x 2N waves of 64x64

    f32x4 acc[4][4] = {};

    int arow[4], acol[4], brow[2], bcol[2];
#pragma unroll
    for (int s = 0; s < 4; ++s) {
        int idx = s * 512 + tid;
        arow[s] = idx >> 3;
        acol[s] = ((idx & 7) ^ (arow[s] & 7)) * 8;
    }
#pragma unroll
    for (int s = 0; s < 2; ++s) {
        int idx = s * 512 + tid;
        brow[s] = idx >> 3;
        bcol[s] = ((idx & 7) ^ (brow[s] & 7)) * 8;
    }

    for (int k0 = 0; k0 < K; k0 += 64) {
#pragma unroll
        for (int s = 0; s < 4; ++s)
            GLD16(A + (size_t)(m0 + arow[s]) * K + k0 + acol[s], lA + (size_t)(s * 512 + tid) * 8);
#pragma unroll
        for (int s = 0; s < 2; ++s)
            GLD16(B + (size_t)(n0 + brow[s]) * K + k0 + bcol[s], lB + (size_t)(s * 512 + tid) * 8);
        __syncthreads();
#pragma unroll
        for (int kk = 0; kk < 64; kk += 32) {
            int koff = (kk + (lane >> 4) * 8) * 2;
            bf16x8 af[4], bfr[4];
#pragma unroll
            for (int m = 0; m < 4; ++m) {
                int row = wr * 64 + m * 16 + (lane & 15);
                af[m] = *(const bf16x8*)((const char*)lA + ((row * 128 + koff) ^ ((row & 7) << 4)));
            }
#pragma unroll
            for (int n = 0; n < 4; ++n) {
                int row = wc * 64 + n * 16 + (lane & 15);
                bfr[n] = *(const bf16x8*)((const char*)lB + ((row * 128 + koff) ^ ((row & 7) << 4)));
            }
#pragma unroll
            for (int m = 0; m < 4; ++m)
#pragma unroll
                for (int n = 0; n < 4; ++n)
                    acc[m][n] = __builtin_amdgcn_mfma_f32_16x16x32_bf16(af[m], bfr[n], acc[m][n], 0, 0, 0);
        }
        __syncthreads();
    }

    int rl = (lane >> 4) * 4;
    int cl = lane & 15;
    unsigned short* Cb = C + (size_t)bz * sC;
#pragma unroll
    for (int m = 0; m < 4; ++m)
#pragma unroll
        for (int n = 0; n < 4; ++n) {
            int gm = m0 + wr * 64 + m * 16 + rl;
            int gn = n0 + wc * 64 + n * 16 + cl;
#pragma unroll
            for (int rg = 0; rg < 4; ++rg) {
                float v = acc[m][n][rg];
                if (EPI == 0) v += bias[gn];
                if (EPI == 1) v += bias[gm + rg];
                Cb[(size_t)(gm + rg) * N + gn] = f2bf(v);
            }
        }
}

// ================= scores GEMM (256x128): E = exp2(t - Mtile) bf16 + tile stats =======
__global__ __launch_bounds__(512, 4)
void scores_gemm(const unsigned short* __restrict__ T1, const unsigned short* __restrict__ xnT,
                 unsigned short* __restrict__ S, float* __restrict__ tmax, float* __restrict__ tsum) {
    unsigned nx = gridDim.x, ny = gridDim.y;
    unsigned lin = blockIdx.x + nx * (blockIdx.y + ny * blockIdx.z);
    unsigned nwg = nx * ny * gridDim.z;
    unsigned work = (lin & 7) * (nwg >> 3) + (lin >> 3);
    unsigned bx = work % nx; work /= nx;
    unsigned by = work % ny;
    unsigned bz = work / ny;

    const unsigned short* Ab = T1 + (size_t)bz * HW * CD;
    const unsigned short* Bb = xnT + (size_t)bz * HW * CD;
    int m0 = by * 256, n0 = bx * 128;

    __shared__ unsigned short lA[256 * 64];
    __shared__ unsigned short lB[128 * 64];
    __shared__ float redm[2][256];
    __shared__ float reds[2][256];

    int tid = threadIdx.x, lane = tid & 63;
    int wid = tid >> 6;
    int wr = wid >> 1, wc = wid & 1;

    f32x4 acc[4][4] = {};

    int arow[4], acol[4], brow[2], bcol[2];
#pragma unroll
    for (int s = 0; s < 4; ++s) {
        int idx = s * 512 + tid;
        arow[s] = idx >> 3;
        acol[s] = ((idx & 7) ^ (arow[s] & 7)) * 8;
    }
#pragma unroll
    for (int s = 0; s < 2; ++s) {
        int idx = s * 512 + tid;
        brow[s] = idx >> 3;
        bcol[s] = ((idx & 7) ^ (brow[s] & 7)) * 8;
    }

    for (int k0 = 0; k0 < CD; k0 += 64) {
#pragma unroll
        for (int s = 0; s < 4; ++s)
            GLD16(Ab + (size_t)(m0 + arow[s]) * CD + k0 + acol[s], lA + (size_t)(s * 512 + tid) * 8);
#pragma unroll
        for (int s = 0; s < 2; ++s)
            GLD16(Bb + (size_t)(n0 + brow[s]) * CD + k0 + bcol[s], lB + (size_t)(s * 512 + tid) * 8);
        __syncthreads();
#pragma unroll
        for (int kk = 0; kk < 64; kk += 32) {
            int koff = (kk + (lane >> 4) * 8) * 2;
            bf16x8 af[4], bfr[4];
#pragma unroll
            for (int m = 0; m < 4; ++m) {
                int row = wr * 64 + m * 16 + (lane & 15);
                af[m] = *(const bf16x8*)((const char*)lA + ((row * 128 + koff) ^ ((row & 7) << 4)));
            }
#pragma unroll
            for (int n = 0; n < 4; ++n) {
                int row = wc * 64 + n * 16 + (lane & 15);
                bfr[n] = *(const bf16x8*)((const char*)lB + ((row * 128 + koff) ^ ((row & 7) << 4)));
            }
#pragma unroll
            for (int m = 0; m < 4; ++m)
#pragma unroll
                for (int n = 0; n < 4; ++n)
                    acc[m][n] = __builtin_amdgcn_mfma_f32_16x16x32_bf16(af[m], bfr[n], acc[m][n], 0, 0, 0);
        }
        __syncthreads();
    }

    const float SL2E = 0.044194173824159216f * 1.4426950408889634f;
#pragma unroll
    for (int m = 0; m < 4; ++m)
#pragma unroll
        for (int n = 0; n < 4; ++n) acc[m][n] *= SL2E;

    int rl = (lane >> 4) * 4;
    int cl = lane & 15;

    float mr[4][4];
#pragma unroll
    for (int m = 0; m < 4; ++m)
#pragma unroll
        for (int rg = 0; rg < 4; ++rg)
            mr[m][rg] = fmaxf(fmaxf(acc[m][0][rg], acc[m][1][rg]),
                              fmaxf(acc[m][2][rg], acc[m][3][rg]));
#pragma unroll
    for (int d = 1; d < 16; d <<= 1)
#pragma unroll
        for (int m = 0; m < 4; ++m)
#pragma unroll
            for (int rg = 0; rg < 4; ++rg) mr[m][rg] = fmaxf(mr[m][rg], __shfl_xor(mr[m][rg], d));
    if ((lane & 15) == 0)
#pragma unroll
        for (int m = 0; m < 4; ++m)
#pragma unroll
            for (int rg = 0; rg < 4; ++rg) redm[wc][wr * 64 + m * 16 + rl + rg] = mr[m][rg];
    __syncthreads();
    float Mt[4][4];
#pragma unroll
    for (int m = 0; m < 4; ++m)
#pragma unroll
        for (int rg = 0; rg < 4; ++rg) {
            int row = wr * 64 + m * 16 + rl + rg;
            Mt[m][rg] = fmaxf(redm[0][row], redm[1][row]);
        }

    float sr[4][4] = {};
#pragma unroll
    for (int m = 0; m < 4; ++m)
#pragma unroll
        for (int n = 0; n < 4; ++n)
#pragma unroll
            for (int rg = 0; rg < 4; ++rg) {
                float e = __builtin_amdgcn_exp2f(acc[m][n][rg] - Mt[m][rg]);
                acc[m][n][rg] = e;
                sr[m][rg] += e;
            }
#pragma unroll
    for (int d = 1; d < 16; d <<= 1)
#pragma unroll
        for (int m = 0; m < 4; ++m)
#pragma unroll
            for (int rg = 0; rg < 4; ++rg) sr[m][rg] += __shfl_xor(sr[m][rg], d);
    if ((lane & 15) == 0)
#pragma unroll
        for (int m = 0; m < 4; ++m)
#pragma unroll
            for (int rg = 0; rg < 4; ++rg) reds[wc][wr * 64 + m * 16 + rl + rg] = sr[m][rg];
    __syncthreads();

    if (tid < 256) {
        float M = fmaxf(redm[0][tid], redm[1][tid]);
        float Z = reds[0][tid] + reds[1][tid];
        size_t o = ((size_t)bz * 8 + bx) * HW + m0 + tid;
        tmax[o] = M;
        tsum[o] = Z;
    }

    unsigned short* Sb = S + (size_t)bz * HW * HW;
#pragma unroll
    for (int m = 0; m < 4; ++m)
#pragma unroll
        for (int n = 0; n < 4; ++n) {
            int gm = m0 + wr * 64 + m * 16 + rl;
            int gn = n0 + wc * 64 + n * 16 + cl;
#pragma unroll
            for (int rg = 0; rg < 4; ++rg)
                Sb[(size_t)(gm + rg) * HW + gn] = f2bf(acc[m][n][rg]);
        }
}

// ---------------- Horner ratios (unchanged)
__global__ __launch_bounds__(256)
void rescale_kernel(const float* __restrict__ tmax, const float* __restrict__ tsum,
                    float* __restrict__ ratio) {
    int r = blockIdx.x * 256 + threadIdx.x;
    int b = r >> 10, i = r & 1023;
    const float* tm = tmax + (size_t)b * 8 * HW + i;
    const float* ts = tsum + (size_t)b * 8 * HW + i;
    float M = -1e30f;
#pragma unroll
    for (int jt = 0; jt < 8; ++jt) M = fmaxf(M, tm[(size_t)jt * HW]);
    float Z = 0.f;
#pragma unroll
    for (int jt = 0; jt < 8; ++jt) Z += ts[(size_t)jt * HW] * __builtin_amdgcn_exp2f(tm[(size_t)jt * HW] - M);
    float rZ = 1.0f / Z;
#pragma unroll
    for (int jt = 0; jt < 7; ++jt)
        ratio[((size_t)b * 8 + jt) * HW + i] =
            __builtin_amdgcn_exp2f(tm[(size_t)jt * HW] - tm[(size_t)(jt + 1) * HW]);
    ratio[((size_t)b * 8 + 7) * HW + i] = __builtin_amdgcn_exp2f(tm[(size_t)7 * HW] - M) * rZ;
}

// ================= PV GEMM (256x128): single acc + Horner rescale per j-tile ==========
__global__ __launch_bounds__(512, 4)
void pv_gemm(const unsigned short* __restrict__ A, const unsigned short* __restrict__ B,
             float* __restrict__ C, const float* __restrict__ bias,
             const float* __restrict__ resid, const float* __restrict__ ratio) {
    unsigned nx = gridDim.x, ny = gridDim.y;
    unsigned lin = blockIdx.x + nx * (blockIdx.y + ny * blockIdx.z);
    unsigned nwg = nx * ny * gridDim.z;
    unsigned work = (lin & 7) * (nwg >> 3) + (lin >> 3);
    unsigned bx = work % nx; work /= nx;
    unsigned by = work % ny;
    unsigned bz = work / ny;

    A += (size_t)bz * 512 * 1024;
    B += (size_t)bz * 1024 * 1024;
    int m0 = by * 256, n0 = bx * 128;

    __shared__ unsigned short lA[256 * 64];
    __shared__ unsigned short lB[128 * 64];

    int tid = threadIdx.x, lane = tid & 63;
    int wid = tid >> 6;
    int wr = wid >> 1, wc = wid & 1;
    int cl = lane & 15;

    f32x4 acc[4][4] = {};

    int arow[4], acol[4], brow[2], bcol[2];
#pragma unroll
    for (int s = 0; s < 4; ++s) {
        int idx = s * 512 + tid;
        arow[s] = idx >> 3;
        acol[s] = ((idx & 7) ^ (arow[s] & 7)) * 8;
    }
#pragma unroll
    for (int s = 0; s < 2; ++s) {
        int idx = s * 512 + tid;
        brow[s] = idx >> 3;
        bcol[s] = ((idx & 7) ^ (brow[s] & 7)) * 8;
    }

    const float* rbase = ratio + (size_t)bz * 8 * HW + n0 + wc * 64 + cl;

    for (int jt = 0; jt < 8; ++jt) {
        float r0 = rbase[(size_t)jt * HW + 0];
        float r1 = rbase[(size_t)jt * HW + 16];
        float r2 = rbase[(size_t)jt * HW + 32];
        float r3 = rbase[(size_t)jt * HW + 48];
#pragma unroll
        for (int t2 = 0; t2 < 2; ++t2) {
            int k0 = jt * 128 + t2 * 64;
#pragma unroll
            for (int s = 0; s < 4; ++s)
                GLD16(A + (size_t)(m0 + arow[s]) * 1024 + k0 + acol[s], lA + (size_t)(s * 512 + tid) * 8);
#pragma unroll
            for (int s = 0; s < 2; ++s)
                GLD16(B + (size_t)(n0 + brow[s]) * 1024 + k0 + bcol[s], lB + (size_t)(s * 512 + tid) * 8);
            __syncthreads();
#pragma unroll
            for (int kk = 0; kk < 64; kk += 32) {
                int koff = (kk + (lane >> 4) * 8) * 2;
                bf16x8 af[4], bfr[4];
#pragma unroll
                for (int m = 0; m < 4; ++m) {
                    int row = wr * 64 + m * 16 + (lane & 15);
                    af[m] = *(const bf16x8*)((const char*)lA + ((row * 128 + koff) ^ ((row & 7) << 4)));
                }
#pragma unroll
                for (int n = 0; n < 4; ++n) {
                    int row = wc * 64 + n * 16 + (lane & 15);
                    bfr[n] = *(const bf16x8*)((const char*)lB + ((row * 128 + koff) ^ ((row & 7) << 4)));
                }
#pragma unroll
                for (int m = 0; m < 4; ++m)
#pragma unroll
                    for (int n = 0; n < 4; ++n)
                        acc[m][n] = __builtin_amdgcn_mfma_f32_16x16x32_bf16(af[m], bfr[n], acc[m][n], 0, 0, 0);
            }
            __syncthreads();
        }
#pragma unroll
        for (int m = 0; m < 4; ++m) {
            acc[m][0] *= r0;
            acc[m][1] *= r1;
            acc[m][2] *= r2;
            acc[m][3] *= r3;
        }
    }

    int rl = (lane >> 4) * 4;
    float* Cf = C + (size_t)bz * 512 * 1024;
    const float* Rs = resid + (size_t)bz * 512 * 1024;
#pragma unroll
    for (int m = 0; m < 4; ++m)
#pragma unroll
        for (int n = 0; n < 4; ++n) {
            int gm = m0 + wr * 64 + m * 16 + rl;
            int gn = n0 + wc * 64 + n * 16 + cl;
#pragma unroll
            for (int rg = 0; rg < 4; ++rg) {
                size_t off = (size_t)(gm + rg) * 1024 + gn;
                Cf[off] = acc[m][n][rg] + bias[gm + rg] + Rs[off];
            }
        }
}

// ---------------- launch
extern "C" void kernel_launch(void* const* d_in, const int* in_sizes, int n_in,
                              void* d_out, int out_size, void* d_ws, size_t ws_size,
                              hipStream_t stream) {
    const float* x      = (const float*)d_in[0];
    const float* gamma  = (const float*)d_in[1];
    const float* beta   = (const float*)d_in[2];
    const float* qkv_w  = (const float*)d_in[3];
    const float* qkv_b  = (const float*)d_in[4];
    const float* out_w  = (const float*)d_in[5];
    const float* out_b  = (const float*)d_in[6];

    char* ws = (char*)d_ws;
    unsigned short* xnT  = (unsigned short*)ws;                   // 32 MB
    unsigned short* vpr  = (unsigned short*)(ws + 33554432);      // 32 MB
    unsigned short* SP   = (unsigned short*)(ws + 67108864);      // 32 MB (half-batch E)
    unsigned short* wqkT = (unsigned short*)(ws + 100663296);     // 512 KB
    unsigned short* w2   = (unsigned short*)(ws + 101187584);     // 512 KB
    float* gvec          = (float*)(ws + 101711872);
    float* bias2         = (float*)(ws + 101713920);
    float* meanp         = (float*)(ws + 101715968);
    float* rstdp         = (float*)(ws + 101716992);
    float* tmaxp         = (float*)(ws + 101718016);              // 1 MB
    float* tsump         = (float*)(ws + 102766592);              // 1 MB
    float* ratiop        = (float*)(ws + 103815168);              // 512 KB (per half)

    // transient weight-prep slots in the SP region
    unsigned short* slot0 = SP;
    unsigned short* owb   = SP + 786432;

    unsigned short* T1 = (unsigned short*)((char*)d_out + 33554432);
    float* outF = (float*)d_out;

    const float* wk_f = qkv_w + (size_t)512 * CD;

    gn_stats<<<256, 256, 0, stream>>>(x, meanp, rstdp);
    gn_norm_t<<<dim3(16, 8, 32), 256, 0, stream>>>(x, meanp, rstdp, gamma, beta, xnT);

    tpose3_bf16<<<dim3(8, 8, 3), 256, 0, stream>>>(qkv_w, slot0);
    cvt_bf16<<<256, 256, 0, stream>>>(out_w, owb);
    gvec_kernel<<<8, 256, 0, stream>>>(wk_f, qkv_b, gvec);
    bias2_kernel<<<128, 256, 0, stream>>>(out_w, qkv_b + 1024, bias2);

    // z=0: wqkT = wkT . wqT^T ; z=1: w2 = owb . wvT^T
    gemm_w<<<dim3(4, 4, 2), 256, 0, stream>>>(slot0 + 524288, slot0, wqkT,
        512, 262144, 262144, 262144);

    // T1[b,i,d] = xnT[b,i,:] . wqkT[d,:] + g[d]
    gemm_bt2<0><<<dim3(4, 4, 32), 512, 0, stream>>>(xnT, wqkT, T1, gvec,
        1024, 512, 512, 1024LL * 512, 0, 1024LL * 512);
    // vpr[b,o,i] = w2[o,:] . xnT[b,i,:] + bias2[o]
    gemm_bt2<1><<<dim3(8, 2, 32), 512, 0, stream>>>(w2, xnT, vpr, bias2,
        512, 1024, 512, 0, 1024LL * 512, 512LL * 1024);

    for (int h = 0; h < 2; ++h) {
        const unsigned short* T1h = T1 + (size_t)h * 16 * 1024 * 512;
        const unsigned short* xh  = xnT + (size_t)h * 16 * 1024 * 512;
        float* tmaxh = tmaxp + (size_t)h * 16 * 8 * 1024;
        float* tsumh = tsump + (size_t)h * 16 * 8 * 1024;

        scores_gemm<<<dim3(8, 4, 16), 512, 0, stream>>>(T1h, xh, SP, tmaxh, tsumh);
        rescale_kernel<<<64, 256, 0, stream>>>(tmaxh, tsumh, ratiop);
        pv_gemm<<<dim3(8, 2, 16), 512, 0, stream>>>(
            vpr + (size_t)h * 16 * 512 * 1024, SP,
            outF + (size_t)h * 16 * 512 * 1024, out_b,
            x + (size_t)h * 16 * 512 * 1024, ratiop);
    }
    (void)in_sizes; (void)n_in; (void)out_size; (void)ws_size;
}

// Round 14
// 225.776 us; speedup vs baseline: 1.2251x; 1.2251x over previous
//
#include <hip/hip_runtime.h>

#define HW 1024
#define CD 512

typedef __bf16 bf16x8 __attribute__((ext_vector_type(8)));
typedef float f32x4 __attribute__((ext_vector_type(4)));

__device__ __forceinline__ unsigned short f2bf(float f) {
    unsigned int u = __float_as_uint(f);
    u += 0x7fff + ((u >> 16) & 1);   // RNE
    return (unsigned short)(u >> 16);
}
__device__ __forceinline__ float bf2f(unsigned short h) {
    return __uint_as_float((unsigned)h << 16);
}

#define AS1(p) ((__attribute__((address_space(1))) void*)(p))
#define AS3(p) ((__attribute__((address_space(3))) void*)(p))
#define GLD16(gp, lp) __builtin_amdgcn_global_load_lds(AS1(gp), AS3(lp), 16, 0, 0)

// ---------------- GroupNorm stats: one block per (b,g)
__global__ __launch_bounds__(256)
void gn_stats(const float* __restrict__ x, float* __restrict__ mean, float* __restrict__ rstd) {
    int bg = blockIdx.x;
    const float4* p4 = (const float4*)(x + (size_t)bg * 65536);
    int tid = threadIdx.x;
    float s = 0.f, ss = 0.f;
#pragma unroll 8
    for (int it = 0; it < 64; ++it) {
        float4 v = p4[tid + it * 256];
        s  += v.x + v.y + v.z + v.w;
        ss += v.x * v.x + v.y * v.y + v.z * v.z + v.w * v.w;
    }
#pragma unroll
    for (int d = 32; d > 0; d >>= 1) { s += __shfl_down(s, d); ss += __shfl_down(ss, d); }
    __shared__ float ls[4], lss[4];
    if ((tid & 63) == 0) { ls[tid >> 6] = s; lss[tid >> 6] = ss; }
    __syncthreads();
    if (tid == 0) {
        float S = ls[0] + ls[1] + ls[2] + ls[3];
        float SS = lss[0] + lss[1] + lss[2] + lss[3];
        float m = S * (1.f / 65536.f);
        float v = SS * (1.f / 65536.f) - m * m;
        mean[bg] = m;
        rstd[bg] = rsqrtf(v + 1e-5f);
    }
}

// ---------------- normalize + transpose: x[b,c,hw] f32 -> xnT[b,hw,c] bf16 (pad 67)
__global__ __launch_bounds__(256)
void gn_norm_t(const float* __restrict__ x, const float* __restrict__ mean, const float* __restrict__ rstd,
               const float* __restrict__ gamma, const float* __restrict__ beta,
               unsigned short* __restrict__ xnT) {
    __shared__ unsigned short tile[64][67];
    int i0 = blockIdx.x * 64, c0 = blockIdx.y * 64, b = blockIdx.z;
    float m = mean[b * 8 + blockIdx.y];
    float r = rstd[b * 8 + blockIdx.y];
    int tid = threadIdx.x;
    int tr = tid >> 4, tc = (tid & 15) * 4;
    const float* xb = x + ((size_t)b * CD + c0) * HW + i0;
#pragma unroll
    for (int p = 0; p < 4; ++p) {
        int c = tr + p * 16;
        float g = gamma[c0 + c] * r;
        float bb = beta[c0 + c] - m * g;
        float4 v = *(const float4*)(xb + (size_t)c * HW + tc);
        tile[c][tc + 0] = f2bf(v.x * g + bb);
        tile[c][tc + 1] = f2bf(v.y * g + bb);
        tile[c][tc + 2] = f2bf(v.z * g + bb);
        tile[c][tc + 3] = f2bf(v.w * g + bb);
    }
    __syncthreads();
    unsigned short* ob = xnT + ((size_t)b * HW + i0) * CD + c0;
#pragma unroll
    for (int p = 0; p < 4; ++p) {
        int ir = tr + p * 16;
        ushort4 u;
        u.x = tile[tc + 0][ir];
        u.y = tile[tc + 1][ir];
        u.z = tile[tc + 2][ir];
        u.w = tile[tc + 3][ir];
        *(ushort4*)(ob + (size_t)ir * CD + tc) = u;
    }
}

// ---------------- transpose + cvt x3: qkv_w row-blocks -> bf16 transposed (pad 67)
// slot map: wq -> slot0, wk -> slot2, wv -> slot1  (pairs A=[wkT][owb], B=[wqT][wvT])
__global__ __launch_bounds__(256)
void tpose3_bf16(const float* __restrict__ qkv_w, unsigned short* __restrict__ dst0) {
    __shared__ unsigned short tile[64][67];
    const int zmap[3] = {0, 2, 1};
    const float* src = qkv_w + (size_t)blockIdx.z * CD * CD;
    unsigned short* dst = dst0 + (size_t)zmap[blockIdx.z] * CD * CD;
    int i0 = blockIdx.x * 64, c0 = blockIdx.y * 64;
    int tid = threadIdx.x;
    int tr = tid >> 4, tc = (tid & 15) * 4;
#pragma unroll
    for (int p = 0; p < 4; ++p) {
        int r = tr + p * 16;
        float4 v = *(const float4*)(src + (size_t)(i0 + r) * CD + c0 + tc);
        tile[r][tc + 0] = f2bf(v.x);
        tile[r][tc + 1] = f2bf(v.y);
        tile[r][tc + 2] = f2bf(v.z);
        tile[r][tc + 3] = f2bf(v.w);
    }
    __syncthreads();
#pragma unroll
    for (int p = 0; p < 4; ++p) {
        int ir = tr + p * 16;
        ushort4 u;
        u.x = tile[tc + 0][ir];
        u.y = tile[tc + 1][ir];
        u.z = tile[tc + 2][ir];
        u.w = tile[tc + 3][ir];
        *(ushort4*)(dst + (size_t)(c0 + ir) * CD + i0 + tc) = u;
    }
}

// ---------------- f32 -> bf16 convert
__global__ __launch_bounds__(256)
void cvt_bf16(const float* __restrict__ src, unsigned short* __restrict__ dst) {
    int i = blockIdx.x * 256 + threadIdx.x;
    float4 v = ((const float4*)src)[i];
    ushort4 u;
    u.x = f2bf(v.x); u.y = f2bf(v.y); u.z = f2bf(v.z); u.w = f2bf(v.w);
    ((ushort4*)dst)[i] = u;
}

// ---------------- g[d] = sum_o wk[o][d] * bq[o]
__global__ __launch_bounds__(256)
void gvec_kernel(const float* __restrict__ wk, const float* __restrict__ bq,
                 float* __restrict__ g) {
    __shared__ float red[4][64];
    int d = blockIdx.x * 64 + (threadIdx.x & 63);
    int os = threadIdx.x >> 6;
    float acc = 0.f;
    for (int o = os * 128; o < os * 128 + 128; ++o)
        acc += wk[(size_t)o * CD + d] * bq[o];
    red[os][threadIdx.x & 63] = acc;
    __syncthreads();
    if (threadIdx.x < 64)
        g[blockIdx.x * 64 + threadIdx.x] = red[0][threadIdx.x] + red[1][threadIdx.x] +
                                           red[2][threadIdx.x] + red[3][threadIdx.x];
}

// ---------------- bias2[o] = sum_t out_w[o][t] * bv[t]
__global__ __launch_bounds__(256)
void bias2_kernel(const float* __restrict__ out_w, const float* __restrict__ bv,
                  float* __restrict__ bias2) {
    int wid = threadIdx.x >> 6, lane = threadIdx.x & 63;
    int o = blockIdx.x * 4 + wid;
    float acc = 0.f;
#pragma unroll
    for (int t = 0; t < 512; t += 64)
        acc += out_w[(size_t)o * CD + t + lane] * bv[t + lane];
#pragma unroll
    for (int d = 32; d > 0; d >>= 1) acc += __shfl_down(acc, d);
    if (lane == 0) bias2[o] = acc;
}

// ---------------- generic bf16 GEMM (128x128, proven structure)
// EPI 0: bf16 + bias[col] | 1: bf16 + bias[row] | 3: bf16 no bias
template<int EPI>
__global__ __launch_bounds__(256, 2)
void gemm_bt(const unsigned short* __restrict__ A, const unsigned short* __restrict__ B,
             void* __restrict__ Cv, const float* __restrict__ bias,
             int M, int N, int K, long long sA, long long sB, long long sC) {
    unsigned nx = gridDim.x, ny = gridDim.y;
    unsigned lin = blockIdx.x + nx * (blockIdx.y + ny * blockIdx.z);
    unsigned nwg = nx * ny * gridDim.z;
    unsigned work = (lin & 7) * (nwg >> 3) + (lin >> 3);
    unsigned bx = work % nx; work /= nx;
    unsigned by = work % ny;
    unsigned bz = work / ny;

    A += (size_t)bz * sA;
    B += (size_t)bz * sB;
    int m0 = by * 128, n0 = bx * 128;

    __shared__ unsigned short lA[128 * 64];
    __shared__ unsigned short lB[128 * 64];

    int tid = threadIdx.x;
    int lane = tid & 63;
    int wr = (tid >> 6) >> 1, wc = (tid >> 6) & 1;

    f32x4 acc[4][4] = {};

    int strow[4], stcol[4];
#pragma unroll
    for (int s = 0; s < 4; ++s) {
        int row = (s * 256 + tid) >> 3;
        int g = (tid & 7) ^ (row & 7);
        strow[s] = row;
        stcol[s] = g * 8;
    }

    for (int k0 = 0; k0 < K; k0 += 64) {
#pragma unroll
        for (int s = 0; s < 4; ++s) {
            GLD16(A + (size_t)(m0 + strow[s]) * K + k0 + stcol[s], lA + (size_t)(s * 256 + tid) * 8);
            GLD16(B + (size_t)(n0 + strow[s]) * K + k0 + stcol[s], lB + (size_t)(s * 256 + tid) * 8);
        }
        __syncthreads();
#pragma unroll
        for (int kk = 0; kk < 64; kk += 32) {
            bf16x8 af[4], bfr[4];
#pragma unroll
            for (int m = 0; m < 4; ++m) {
                int row = wr * 64 + m * 16 + (lane & 15);
                int off = (row * 128 + (kk + (lane >> 4) * 8) * 2) ^ ((row & 7) << 4);
                af[m] = *(const bf16x8*)((const char*)lA + off);
            }
#pragma unroll
            for (int n = 0; n < 4; ++n) {
                int row = wc * 64 + n * 16 + (lane & 15);
                int off = (row * 128 + (kk + (lane >> 4) * 8) * 2) ^ ((row & 7) << 4);
                bfr[n] = *(const bf16x8*)((const char*)lB + off);
            }
#pragma unroll
            for (int m = 0; m < 4; ++m)
#pragma unroll
                for (int n = 0; n < 4; ++n)
                    acc[m][n] = __builtin_amdgcn_mfma_f32_16x16x32_bf16(af[m], bfr[n], acc[m][n], 0, 0, 0);
        }
        __syncthreads();
    }

    int rl = (lane >> 4) * 4;
    int cl = lane & 15;
    unsigned short* Cb = (unsigned short*)Cv + (size_t)bz * sC;
#pragma unroll
    for (int m = 0; m < 4; ++m)
#pragma unroll
        for (int n = 0; n < 4; ++n) {
            int gm = m0 + wr * 64 + m * 16 + rl;
            int gn = n0 + wc * 64 + n * 16 + cl;
#pragma unroll
            for (int rg = 0; rg < 4; ++rg) {
                float v = acc[m][n][rg];
                if (EPI == 0) v += bias[gn];
                if (EPI == 1) v += bias[gm + rg];
                Cb[(size_t)(gm + rg) * N + gn] = f2bf(v);
            }
        }
}

// ---------------- scores GEMM: stores E = exp2((T1.xn)*scale*log2e - Mtile) bf16
// + per-(row, col-tile) stats tmax/tsum.
__global__ __launch_bounds__(256, 2)
void scores_gemm(const unsigned short* __restrict__ T1, const unsigned short* __restrict__ xnT,
                 unsigned short* __restrict__ S, float* __restrict__ tmax, float* __restrict__ tsum) {
    unsigned nx = gridDim.x, ny = gridDim.y;
    unsigned lin = blockIdx.x + nx * (blockIdx.y + ny * blockIdx.z);
    unsigned nwg = nx * ny * gridDim.z;
    unsigned work = (lin & 7) * (nwg >> 3) + (lin >> 3);
    unsigned bx = work % nx; work /= nx;
    unsigned by = work % ny;
    unsigned bz = work / ny;

    const unsigned short* Ab = T1 + (size_t)bz * HW * CD;
    const unsigned short* Bb = xnT + (size_t)bz * HW * CD;
    int m0 = by * 128, n0 = bx * 128;

    __shared__ unsigned short lA[128 * 64];
    __shared__ unsigned short lB[128 * 64];
    __shared__ float redm[2][128];
    __shared__ float reds[2][128];

    int tid = threadIdx.x, lane = tid & 63;
    int wr = (tid >> 6) >> 1, wc = (tid >> 6) & 1;

    f32x4 acc[4][4] = {};
    int strow[4], stcol[4];
#pragma unroll
    for (int s = 0; s < 4; ++s) {
        int row = (s * 256 + tid) >> 3;
        int g = (tid & 7) ^ (row & 7);
        strow[s] = row;
        stcol[s] = g * 8;
    }

    for (int k0 = 0; k0 < CD; k0 += 64) {
#pragma unroll
        for (int s = 0; s < 4; ++s) {
            GLD16(Ab + (size_t)(m0 + strow[s]) * CD + k0 + stcol[s], lA + (size_t)(s * 256 + tid) * 8);
            GLD16(Bb + (size_t)(n0 + strow[s]) * CD + k0 + stcol[s], lB + (size_t)(s * 256 + tid) * 8);
        }
        __syncthreads();
#pragma unroll
        for (int kk = 0; kk < 64; kk += 32) {
            bf16x8 af[4], bfr[4];
#pragma unroll
            for (int m = 0; m < 4; ++m) {
                int row = wr * 64 + m * 16 + (lane & 15);
                int off = (row * 128 + (kk + (lane >> 4) * 8) * 2) ^ ((row & 7) << 4);
                af[m] = *(const bf16x8*)((const char*)lA + off);
            }
#pragma unroll
            for (int n = 0; n < 4; ++n) {
                int row = wc * 64 + n * 16 + (lane & 15);
                int off = (row * 128 + (kk + (lane >> 4) * 8) * 2) ^ ((row & 7) << 4);
                bfr[n] = *(const bf16x8*)((const char*)lB + off);
            }
#pragma unroll
            for (int m = 0; m < 4; ++m)
#pragma unroll
                for (int n = 0; n < 4; ++n)
                    acc[m][n] = __builtin_amdgcn_mfma_f32_16x16x32_bf16(af[m], bfr[n], acc[m][n], 0, 0, 0);
        }
        __syncthreads();
    }

    const float SL2E = 0.044194173824159216f * 1.4426950408889634f;
#pragma unroll
    for (int m = 0; m < 4; ++m)
#pragma unroll
        for (int n = 0; n < 4; ++n) acc[m][n] *= SL2E;

    int rl = (lane >> 4) * 4;
    int cl = lane & 15;

    float mr[4][4];
#pragma unroll
    for (int m = 0; m < 4; ++m)
#pragma unroll
        for (int rg = 0; rg < 4; ++rg)
            mr[m][rg] = fmaxf(fmaxf(acc[m][0][rg], acc[m][1][rg]),
                              fmaxf(acc[m][2][rg], acc[m][3][rg]));
#pragma unroll
    for (int d = 1; d < 16; d <<= 1)
#pragma unroll
        for (int m = 0; m < 4; ++m)
#pragma unroll
            for (int rg = 0; rg < 4; ++rg) mr[m][rg] = fmaxf(mr[m][rg], __shfl_xor(mr[m][rg], d));
    if ((lane & 15) == 0)
#pragma unroll
        for (int m = 0; m < 4; ++m)
#pragma unroll
            for (int rg = 0; rg < 4; ++rg) redm[wc][wr * 64 + m * 16 + rl + rg] = mr[m][rg];
    __syncthreads();
    float Mt[4][4];
#pragma unroll
    for (int m = 0; m < 4; ++m)
#pragma unroll
        for (int rg = 0; rg < 4; ++rg) {
            int row = wr * 64 + m * 16 + rl + rg;
            Mt[m][rg] = fmaxf(redm[0][row], redm[1][row]);
        }

    float sr[4][4] = {};
#pragma unroll
    for (int m = 0; m < 4; ++m)
#pragma unroll
        for (int n = 0; n < 4; ++n)
#pragma unroll
            for (int rg = 0; rg < 4; ++rg) {
                float e = __builtin_amdgcn_exp2f(acc[m][n][rg] - Mt[m][rg]);
                acc[m][n][rg] = e;
                sr[m][rg] += e;
            }
#pragma unroll
    for (int d = 1; d < 16; d <<= 1)
#pragma unroll
        for (int m = 0; m < 4; ++m)
#pragma unroll
            for (int rg = 0; rg < 4; ++rg) sr[m][rg] += __shfl_xor(sr[m][rg], d);
    if ((lane & 15) == 0)
#pragma unroll
        for (int m = 0; m < 4; ++m)
#pragma unroll
            for (int rg = 0; rg < 4; ++rg) reds[wc][wr * 64 + m * 16 + rl + rg] = sr[m][rg];
    __syncthreads();

    if (tid < 128) {
        float M = fmaxf(redm[0][tid], redm[1][tid]);
        float Z = reds[0][tid] + reds[1][tid];
        size_t o = ((size_t)bz * 8 + bx) * HW + m0 + tid;
        tmax[o] = M;
        tsum[o] = Z;
    }

    unsigned short* Sb = S + (size_t)bz * HW * HW;
#pragma unroll
    for (int m = 0; m < 4; ++m)
#pragma unroll
        for (int n = 0; n < 4; ++n) {
            int gm = m0 + wr * 64 + m * 16 + rl;
            int gn = n0 + wc * 64 + n * 16 + cl;
#pragma unroll
            for (int rg = 0; rg < 4; ++rg)
                Sb[(size_t)(gm + rg) * HW + gn] = f2bf(acc[m][n][rg]);
        }
}

// ---------------- Horner ratios for PV: r[jt][i] = exp2(Mt_jt - Mt_{jt+1}) (jt<7),
//                  r[7][i] = exp2(Mt_7 - Mrow) / Z
__global__ __launch_bounds__(256)
void rescale_kernel(const float* __restrict__ tmax, const float* __restrict__ tsum,
                    float* __restrict__ ratio) {
    int r = blockIdx.x * 256 + threadIdx.x;   // 16*1024 rows per half
    int b = r >> 10, i = r & 1023;
    const float* tm = tmax + (size_t)b * 8 * HW + i;
    const float* ts = tsum + (size_t)b * 8 * HW + i;
    float M = -1e30f;
#pragma unroll
    for (int jt = 0; jt < 8; ++jt) M = fmaxf(M, tm[(size_t)jt * HW]);
    float Z = 0.f;
#pragma unroll
    for (int jt = 0; jt < 8; ++jt) Z += ts[(size_t)jt * HW] * __builtin_amdgcn_exp2f(tm[(size_t)jt * HW] - M);
    float rZ = 1.0f / Z;
#pragma unroll
    for (int jt = 0; jt < 7; ++jt)
        ratio[((size_t)b * 8 + jt) * HW + i] =
            __builtin_amdgcn_exp2f(tm[(size_t)jt * HW] - tm[(size_t)(jt + 1) * HW]);
    ratio[((size_t)b * 8 + 7) * HW + i] = __builtin_amdgcn_exp2f(tm[(size_t)7 * HW] - M) * rZ;
}

// ---------------- PV GEMM: single accumulator + Horner rescale per 128-col j-tile.
__global__ __launch_bounds__(256)
void pv_gemm(const unsigned short* __restrict__ A, const unsigned short* __restrict__ B,
             float* __restrict__ C, const float* __restrict__ bias,
             const float* __restrict__ resid, const float* __restrict__ ratio) {
    unsigned nx = gridDim.x, ny = gridDim.y;
    unsigned lin = blockIdx.x + nx * (blockIdx.y + ny * blockIdx.z);
    unsigned nwg = nx * ny * gridDim.z;
    unsigned work = (lin & 7) * (nwg >> 3) + (lin >> 3);
    unsigned bx = work % nx; work /= nx;
    unsigned by = work % ny;
    unsigned bz = work / ny;

    A += (size_t)bz * 512 * 1024;
    B += (size_t)bz * 1024 * 1024;
    int m0 = by * 128, n0 = bx * 128;

    __shared__ unsigned short lA[128 * 64];
    __shared__ unsigned short lB[128 * 64];

    int tid = threadIdx.x, lane = tid & 63;
    int wr = (tid >> 6) >> 1, wc = (tid >> 6) & 1;
    int cl = lane & 15;

    f32x4 acc[4][4] = {};

    int strow[4], stcol[4];
#pragma unroll
    for (int s = 0; s < 4; ++s) {
        int row = (s * 256 + tid) >> 3;
        int g = (tid & 7) ^ (row & 7);
        strow[s] = row;
        stcol[s] = g * 8;
    }

    const float* rbase = ratio + (size_t)bz * 8 * HW + n0 + wc * 64 + cl;

    for (int jt = 0; jt < 8; ++jt) {
        float r0 = rbase[(size_t)jt * HW + 0];
        float r1 = rbase[(size_t)jt * HW + 16];
        float r2 = rbase[(size_t)jt * HW + 32];
        float r3 = rbase[(size_t)jt * HW + 48];
#pragma unroll
        for (int t2 = 0; t2 < 2; ++t2) {
            int k0 = jt * 128 + t2 * 64;
#pragma unroll
            for (int s = 0; s < 4; ++s) {
                GLD16(A + (size_t)(m0 + strow[s]) * 1024 + k0 + stcol[s], lA + (size_t)(s * 256 + tid) * 8);
                GLD16(B + (size_t)(n0 + strow[s]) * 1024 + k0 + stcol[s], lB + (size_t)(s * 256 + tid) * 8);
            }
            __syncthreads();
#pragma unroll
            for (int kk = 0; kk < 64; kk += 32) {
                bf16x8 af[4], bfr[4];
#pragma unroll
                for (int m = 0; m < 4; ++m) {
                    int row = wr * 64 + m * 16 + (lane & 15);
                    int off = (row * 128 + (kk + (lane >> 4) * 8) * 2) ^ ((row & 7) << 4);
                    af[m] = *(const bf16x8*)((const char*)lA + off);
                }
#pragma unroll
                for (int n = 0; n < 4; ++n) {
                    int row = wc * 64 + n * 16 + (lane & 15);
                    int off = (row * 128 + (kk + (lane >> 4) * 8) * 2) ^ ((row & 7) << 4);
                    bfr[n] = *(const bf16x8*)((const char*)lB + off);
                }
#pragma unroll
                for (int m = 0; m < 4; ++m)
#pragma unroll
                    for (int n = 0; n < 4; ++n)
                        acc[m][n] = __builtin_amdgcn_mfma_f32_16x16x32_bf16(af[m], bfr[n], acc[m][n], 0, 0, 0);
            }
            __syncthreads();
        }
#pragma unroll
        for (int m = 0; m < 4; ++m) {
            acc[m][0] *= r0;
            acc[m][1] *= r1;
            acc[m][2] *= r2;
            acc[m][3] *= r3;
        }
    }

    int rl = (lane >> 4) * 4;
    float* Cf = C + (size_t)bz * 512 * 1024;
    const float* Rs = resid + (size_t)bz * 512 * 1024;
#pragma unroll
    for (int m = 0; m < 4; ++m)
#pragma unroll
        for (int n = 0; n < 4; ++n) {
            int gm = m0 + wr * 64 + m * 16 + rl;
            int gn = n0 + wc * 64 + n * 16 + cl;
#pragma unroll
            for (int rg = 0; rg < 4; ++rg) {
                size_t off = (size_t)(gm + rg) * 1024 + gn;
                Cf[off] = acc[m][n][rg] + bias[gm + rg] + Rs[off];
            }
        }
}

// ---------------- launch
extern "C" void kernel_launch(void* const* d_in, const int* in_sizes, int n_in,
                              void* d_out, int out_size, void* d_ws, size_t ws_size,
                              hipStream_t stream) {
    const float* x      = (const float*)d_in[0];
    const float* gamma  = (const float*)d_in[1];
    const float* beta   = (const float*)d_in[2];
    const float* qkv_w  = (const float*)d_in[3];
    const float* qkv_b  = (const float*)d_in[4];
    const float* out_w  = (const float*)d_in[5];
    const float* out_b  = (const float*)d_in[6];

    char* ws = (char*)d_ws;
    unsigned short* xnT  = (unsigned short*)ws;                   // 32 MB
    unsigned short* vpr  = (unsigned short*)(ws + 33554432);      // 32 MB
    unsigned short* SP   = (unsigned short*)(ws + 67108864);      // 32 MB (half-batch E)
    unsigned short* wqkT = (unsigned short*)(ws + 100663296);     // 512 KB
    unsigned short* w2   = (unsigned short*)(ws + 101187584);     // 512 KB (= wqkT + 262144 elems)
    float* gvec          = (float*)(ws + 101711872);
    float* bias2         = (float*)(ws + 101713920);
    float* meanp         = (float*)(ws + 101715968);
    float* rstdp         = (float*)(ws + 101716992);
    float* tmaxp         = (float*)(ws + 101718016);              // 1 MB
    float* tsump         = (float*)(ws + 102766592);              // 1 MB
    float* ratiop        = (float*)(ws + 103815168);              // 512 KB (per half)

    // transient weight-prep slots in the SP region (dead before scores_gemm writes SP)
    // slot0: wqT, slot1: wvT, slot2: wkT, slot3: owb  (each 262144 elems)
    unsigned short* slot0 = SP;
    unsigned short* owb   = SP + 786432;

    // T1 parked in d_out[32MB..64MB]; PV half-0 writes d_out[0..32MB] only.
    unsigned short* T1 = (unsigned short*)((char*)d_out + 33554432);
    float* outF = (float*)d_out;

    const float* wk_f = qkv_w + (size_t)512 * CD;

    gn_stats<<<256, 256, 0, stream>>>(x, meanp, rstdp);
    gn_norm_t<<<dim3(16, 8, 32), 256, 0, stream>>>(x, meanp, rstdp, gamma, beta, xnT);

    tpose3_bf16<<<dim3(8, 8, 3), 256, 0, stream>>>(qkv_w, slot0);  // wq->s0, wk->s2, wv->s1
    cvt_bf16<<<256, 256, 0, stream>>>(out_w, owb);                 // -> s3
    gvec_kernel<<<8, 256, 0, stream>>>(wk_f, qkv_b, gvec);
    bias2_kernel<<<128, 256, 0, stream>>>(out_w, qkv_b + 1024, bias2);

    // z=0: wqkT = wkT . wqT^T ; z=1: w2 = owb . wvT^T   (A-pair s2,s3; B-pair s0,s1)
    gemm_bt<3><<<dim3(4, 4, 2), 256, 0, stream>>>(slot0 + 524288, slot0, wqkT, nullptr,
        512, 512, 512, 262144, 262144, 262144);

    // T1[b,i,d] = xnT[b,i,:] . wqkT[d,:] + g[d]
    gemm_bt<0><<<dim3(4, 8, 32), 256, 0, stream>>>(xnT, wqkT, T1, gvec,
        1024, 512, 512, 1024LL * 512, 0, 1024LL * 512);
    // vpr[b,o,i] = w2[o,:] . xnT[b,i,:] + bias2[o]
    gemm_bt<1><<<dim3(8, 4, 32), 256, 0, stream>>>(w2, xnT, vpr, bias2,
        512, 1024, 512, 0, 1024LL * 512, 512LL * 1024);

    for (int h = 0; h < 2; ++h) {
        const unsigned short* T1h = T1 + (size_t)h * 16 * 1024 * 512;
        const unsigned short* xh  = xnT + (size_t)h * 16 * 1024 * 512;
        float* tmaxh = tmaxp + (size_t)h * 16 * 8 * 1024;
        float* tsumh = tsump + (size_t)h * 16 * 8 * 1024;

        scores_gemm<<<dim3(8, 8, 16), 256, 0, stream>>>(T1h, xh, SP, tmaxh, tsumh);
        rescale_kernel<<<64, 256, 0, stream>>>(tmaxh, tsumh, ratiop);
        pv_gemm<<<dim3(8, 4, 16), 256, 0, stream>>>(
            vpr + (size_t)h * 16 * 512 * 1024, SP,
            outF + (size_t)h * 16 * 512 * 1024, out_b,
            x + (size_t)h * 16 * 512 * 1024, ratiop);
    }
    (void)in_sizes; (void)n_in; (void)out_size; (void)ws_size;
}

// Round 15
// 222.859 us; speedup vs baseline: 1.2411x; 1.0131x over previous
//
#include <hip/hip_runtime.h>

#define HW 1024
#define CD 512

typedef __bf16 bf16x8 __attribute__((ext_vector_type(8)));
typedef float f32x4 __attribute__((ext_vector_type(4)));

__device__ __forceinline__ unsigned short f2bf(float f) {
    unsigned int u = __float_as_uint(f);
    u += 0x7fff + ((u >> 16) & 1);   // RNE
    return (unsigned short)(u >> 16);
}
__device__ __forceinline__ float bf2f(unsigned short h) {
    return __uint_as_float((unsigned)h << 16);
}

#define AS1(p) ((__attribute__((address_space(1))) void*)(p))
#define AS3(p) ((__attribute__((address_space(3))) void*)(p))
#define GLD16(gp, lp) __builtin_amdgcn_global_load_lds(AS1(gp), AS3(lp), 16, 0, 0)

// ---------------- GroupNorm stats: one block per (b,g)
__global__ __launch_bounds__(256)
void gn_stats(const float* __restrict__ x, float* __restrict__ mean, float* __restrict__ rstd) {
    int bg = blockIdx.x;
    const float4* p4 = (const float4*)(x + (size_t)bg * 65536);
    int tid = threadIdx.x;
    float s = 0.f, ss = 0.f;
#pragma unroll 8
    for (int it = 0; it < 64; ++it) {
        float4 v = p4[tid + it * 256];
        s  += v.x + v.y + v.z + v.w;
        ss += v.x * v.x + v.y * v.y + v.z * v.z + v.w * v.w;
    }
#pragma unroll
    for (int d = 32; d > 0; d >>= 1) { s += __shfl_down(s, d); ss += __shfl_down(ss, d); }
    __shared__ float ls[4], lss[4];
    if ((tid & 63) == 0) { ls[tid >> 6] = s; lss[tid >> 6] = ss; }
    __syncthreads();
    if (tid == 0) {
        float S = ls[0] + ls[1] + ls[2] + ls[3];
        float SS = lss[0] + lss[1] + lss[2] + lss[3];
        float m = S * (1.f / 65536.f);
        float v = SS * (1.f / 65536.f) - m * m;
        mean[bg] = m;
        rstd[bg] = rsqrtf(v + 1e-5f);
    }
}

// ---------------- normalize + transpose: x[b,c,hw] f32 -> xnT[b,hw,c] bf16 (pad 67)
__global__ __launch_bounds__(256)
void gn_norm_t(const float* __restrict__ x, const float* __restrict__ mean, const float* __restrict__ rstd,
               const float* __restrict__ gamma, const float* __restrict__ beta,
               unsigned short* __restrict__ xnT) {
    __shared__ unsigned short tile[64][67];
    int i0 = blockIdx.x * 64, c0 = blockIdx.y * 64, b = blockIdx.z;
    float m = mean[b * 8 + blockIdx.y];
    float r = rstd[b * 8 + blockIdx.y];
    int tid = threadIdx.x;
    int tr = tid >> 4, tc = (tid & 15) * 4;
    const float* xb = x + ((size_t)b * CD + c0) * HW + i0;
#pragma unroll
    for (int p = 0; p < 4; ++p) {
        int c = tr + p * 16;
        float g = gamma[c0 + c] * r;
        float bb = beta[c0 + c] - m * g;
        float4 v = *(const float4*)(xb + (size_t)c * HW + tc);
        tile[c][tc + 0] = f2bf(v.x * g + bb);
        tile[c][tc + 1] = f2bf(v.y * g + bb);
        tile[c][tc + 2] = f2bf(v.z * g + bb);
        tile[c][tc + 3] = f2bf(v.w * g + bb);
    }
    __syncthreads();
    unsigned short* ob = xnT + ((size_t)b * HW + i0) * CD + c0;
#pragma unroll
    for (int p = 0; p < 4; ++p) {
        int ir = tr + p * 16;
        ushort4 u;
        u.x = tile[tc + 0][ir];
        u.y = tile[tc + 1][ir];
        u.z = tile[tc + 2][ir];
        u.w = tile[tc + 3][ir];
        *(ushort4*)(ob + (size_t)ir * CD + tc) = u;
    }
}

// ---------------- transpose + cvt x3: qkv_w row-blocks -> bf16 transposed (pad 67)
// slot map: wq -> slot0, wk -> slot2, wv -> slot1  (pairs A=[wkT][owb], B=[wqT][wvT])
__global__ __launch_bounds__(256)
void tpose3_bf16(const float* __restrict__ qkv_w, unsigned short* __restrict__ dst0) {
    __shared__ unsigned short tile[64][67];
    const int zmap[3] = {0, 2, 1};
    const float* src = qkv_w + (size_t)blockIdx.z * CD * CD;
    unsigned short* dst = dst0 + (size_t)zmap[blockIdx.z] * CD * CD;
    int i0 = blockIdx.x * 64, c0 = blockIdx.y * 64;
    int tid = threadIdx.x;
    int tr = tid >> 4, tc = (tid & 15) * 4;
#pragma unroll
    for (int p = 0; p < 4; ++p) {
        int r = tr + p * 16;
        float4 v = *(const float4*)(src + (size_t)(i0 + r) * CD + c0 + tc);
        tile[r][tc + 0] = f2bf(v.x);
        tile[r][tc + 1] = f2bf(v.y);
        tile[r][tc + 2] = f2bf(v.z);
        tile[r][tc + 3] = f2bf(v.w);
    }
    __syncthreads();
#pragma unroll
    for (int p = 0; p < 4; ++p) {
        int ir = tr + p * 16;
        ushort4 u;
        u.x = tile[tc + 0][ir];
        u.y = tile[tc + 1][ir];
        u.z = tile[tc + 2][ir];
        u.w = tile[tc + 3][ir];
        *(ushort4*)(dst + (size_t)(c0 + ir) * CD + i0 + tc) = u;
    }
}

// ---------------- f32 -> bf16 convert
__global__ __launch_bounds__(256)
void cvt_bf16(const float* __restrict__ src, unsigned short* __restrict__ dst) {
    int i = blockIdx.x * 256 + threadIdx.x;
    float4 v = ((const float4*)src)[i];
    ushort4 u;
    u.x = f2bf(v.x); u.y = f2bf(v.y); u.z = f2bf(v.z); u.w = f2bf(v.w);
    ((ushort4*)dst)[i] = u;
}

// ---------------- g[d] = sum_o wk[o][d] * bq[o]
__global__ __launch_bounds__(256)
void gvec_kernel(const float* __restrict__ wk, const float* __restrict__ bq,
                 float* __restrict__ g) {
    __shared__ float red[4][64];
    int d = blockIdx.x * 64 + (threadIdx.x & 63);
    int os = threadIdx.x >> 6;
    float acc = 0.f;
    for (int o = os * 128; o < os * 128 + 128; ++o)
        acc += wk[(size_t)o * CD + d] * bq[o];
    red[os][threadIdx.x & 63] = acc;
    __syncthreads();
    if (threadIdx.x < 64)
        g[blockIdx.x * 64 + threadIdx.x] = red[0][threadIdx.x] + red[1][threadIdx.x] +
                                           red[2][threadIdx.x] + red[3][threadIdx.x];
}

// ---------------- bias2[o] = sum_t out_w[o][t] * bv[t]
__global__ __launch_bounds__(256)
void bias2_kernel(const float* __restrict__ out_w, const float* __restrict__ bv,
                  float* __restrict__ bias2) {
    int wid = threadIdx.x >> 6, lane = threadIdx.x & 63;
    int o = blockIdx.x * 4 + wid;
    float acc = 0.f;
#pragma unroll
    for (int t = 0; t < 512; t += 64)
        acc += out_w[(size_t)o * CD + t + lane] * bv[t + lane];
#pragma unroll
    for (int d = 32; d > 0; d >>= 1) acc += __shfl_down(acc, d);
    if (lane == 0) bias2[o] = acc;
}

// ---------------- generic bf16 GEMM (128x128, 2-phase dbuf: issue-early + 1 barrier/K-step)
// EPI 0: bf16 + bias[col] | 1: bf16 + bias[row] | 3: bf16 no bias
template<int EPI>
__global__ __launch_bounds__(256, 2)
void gemm_bt(const unsigned short* __restrict__ A, const unsigned short* __restrict__ B,
             void* __restrict__ Cv, const float* __restrict__ bias,
             int M, int N, int K, long long sA, long long sB, long long sC) {
    unsigned nx = gridDim.x, ny = gridDim.y;
    unsigned lin = blockIdx.x + nx * (blockIdx.y + ny * blockIdx.z);
    unsigned nwg = nx * ny * gridDim.z;
    unsigned work = (lin & 7) * (nwg >> 3) + (lin >> 3);
    unsigned bx = work % nx; work /= nx;
    unsigned by = work % ny;
    unsigned bz = work / ny;

    A += (size_t)bz * sA;
    B += (size_t)bz * sB;
    int m0 = by * 128, n0 = bx * 128;

    __shared__ unsigned short lA[2][128 * 64];
    __shared__ unsigned short lB[2][128 * 64];

    int tid = threadIdx.x;
    int lane = tid & 63;
    int wr = (tid >> 6) >> 1, wc = (tid >> 6) & 1;

    f32x4 acc[4][4] = {};

    int strow[4], stcol[4];
#pragma unroll
    for (int s = 0; s < 4; ++s) {
        int row = (s * 256 + tid) >> 3;
        int g = (tid & 7) ^ (row & 7);
        strow[s] = row;
        stcol[s] = g * 8;
    }

    auto stage = [&](int buf, int k0) {
#pragma unroll
        for (int s = 0; s < 4; ++s) {
            GLD16(A + (size_t)(m0 + strow[s]) * K + k0 + stcol[s], &lA[buf][(size_t)(s * 256 + tid) * 8]);
            GLD16(B + (size_t)(n0 + strow[s]) * K + k0 + stcol[s], &lB[buf][(size_t)(s * 256 + tid) * 8]);
        }
    };

    int NT = K >> 6;
    stage(0, 0);
    __syncthreads();
    int cur = 0;
    for (int t = 0; t < NT; ++t) {
        if (t + 1 < NT) stage(cur ^ 1, (t + 1) << 6);   // issue next-tile loads FIRST
        const char* pa = (const char*)lA[cur];
        const char* pb = (const char*)lB[cur];
#pragma unroll
        for (int kk = 0; kk < 64; kk += 32) {
            bf16x8 af[4], bfr[4];
#pragma unroll
            for (int m = 0; m < 4; ++m) {
                int row = wr * 64 + m * 16 + (lane & 15);
                int off = (row * 128 + (kk + (lane >> 4) * 8) * 2) ^ ((row & 7) << 4);
                af[m] = *(const bf16x8*)(pa + off);
            }
#pragma unroll
            for (int n = 0; n < 4; ++n) {
                int row = wc * 64 + n * 16 + (lane & 15);
                int off = (row * 128 + (kk + (lane >> 4) * 8) * 2) ^ ((row & 7) << 4);
                bfr[n] = *(const bf16x8*)(pb + off);
            }
#pragma unroll
            for (int m = 0; m < 4; ++m)
#pragma unroll
                for (int n = 0; n < 4; ++n)
                    acc[m][n] = __builtin_amdgcn_mfma_f32_16x16x32_bf16(af[m], bfr[n], acc[m][n], 0, 0, 0);
        }
        __syncthreads();   // drains this iter's prefetch + syncs LDS reads (one barrier/K-step)
        cur ^= 1;
    }

    int rl = (lane >> 4) * 4;
    int cl = lane & 15;
    unsigned short* Cb = (unsigned short*)Cv + (size_t)bz * sC;
#pragma unroll
    for (int m = 0; m < 4; ++m)
#pragma unroll
        for (int n = 0; n < 4; ++n) {
            int gm = m0 + wr * 64 + m * 16 + rl;
            int gn = n0 + wc * 64 + n * 16 + cl;
#pragma unroll
            for (int rg = 0; rg < 4; ++rg) {
                float v = acc[m][n][rg];
                if (EPI == 0) v += bias[gn];
                if (EPI == 1) v += bias[gm + rg];
                Cb[(size_t)(gm + rg) * N + gn] = f2bf(v);
            }
        }
}

// ---------------- scores GEMM (2-phase dbuf): stores E = exp2(t - Mtile) bf16 + tile stats
__global__ __launch_bounds__(256, 2)
void scores_gemm(const unsigned short* __restrict__ T1, const unsigned short* __restrict__ xnT,
                 unsigned short* __restrict__ S, float* __restrict__ tmax, float* __restrict__ tsum) {
    unsigned nx = gridDim.x, ny = gridDim.y;
    unsigned lin = blockIdx.x + nx * (blockIdx.y + ny * blockIdx.z);
    unsigned nwg = nx * ny * gridDim.z;
    unsigned work = (lin & 7) * (nwg >> 3) + (lin >> 3);
    unsigned bx = work % nx; work /= nx;
    unsigned by = work % ny;
    unsigned bz = work / ny;

    const unsigned short* Ab = T1 + (size_t)bz * HW * CD;
    const unsigned short* Bb = xnT + (size_t)bz * HW * CD;
    int m0 = by * 128, n0 = bx * 128;

    __shared__ unsigned short lA[2][128 * 64];
    __shared__ unsigned short lB[2][128 * 64];
    __shared__ float redm[2][128];
    __shared__ float reds[2][128];

    int tid = threadIdx.x, lane = tid & 63;
    int wr = (tid >> 6) >> 1, wc = (tid >> 6) & 1;

    f32x4 acc[4][4] = {};
    int strow[4], stcol[4];
#pragma unroll
    for (int s = 0; s < 4; ++s) {
        int row = (s * 256 + tid) >> 3;
        int g = (tid & 7) ^ (row & 7);
        strow[s] = row;
        stcol[s] = g * 8;
    }

    auto stage = [&](int buf, int k0) {
#pragma unroll
        for (int s = 0; s < 4; ++s) {
            GLD16(Ab + (size_t)(m0 + strow[s]) * CD + k0 + stcol[s], &lA[buf][(size_t)(s * 256 + tid) * 8]);
            GLD16(Bb + (size_t)(n0 + strow[s]) * CD + k0 + stcol[s], &lB[buf][(size_t)(s * 256 + tid) * 8]);
        }
    };

    stage(0, 0);
    __syncthreads();
    int cur = 0;
    for (int t = 0; t < 8; ++t) {
        if (t < 7) stage(cur ^ 1, (t + 1) << 6);
        const char* pa = (const char*)lA[cur];
        const char* pb = (const char*)lB[cur];
#pragma unroll
        for (int kk = 0; kk < 64; kk += 32) {
            bf16x8 af[4], bfr[4];
#pragma unroll
            for (int m = 0; m < 4; ++m) {
                int row = wr * 64 + m * 16 + (lane & 15);
                int off = (row * 128 + (kk + (lane >> 4) * 8) * 2) ^ ((row & 7) << 4);
                af[m] = *(const bf16x8*)(pa + off);
            }
#pragma unroll
            for (int n = 0; n < 4; ++n) {
                int row = wc * 64 + n * 16 + (lane & 15);
                int off = (row * 128 + (kk + (lane >> 4) * 8) * 2) ^ ((row & 7) << 4);
                bfr[n] = *(const bf16x8*)(pb + off);
            }
#pragma unroll
            for (int m = 0; m < 4; ++m)
#pragma unroll
                for (int n = 0; n < 4; ++n)
                    acc[m][n] = __builtin_amdgcn_mfma_f32_16x16x32_bf16(af[m], bfr[n], acc[m][n], 0, 0, 0);
        }
        __syncthreads();
        cur ^= 1;
    }

    const float SL2E = 0.044194173824159216f * 1.4426950408889634f;
#pragma unroll
    for (int m = 0; m < 4; ++m)
#pragma unroll
        for (int n = 0; n < 4; ++n) acc[m][n] *= SL2E;

    int rl = (lane >> 4) * 4;
    int cl = lane & 15;

    float mr[4][4];
#pragma unroll
    for (int m = 0; m < 4; ++m)
#pragma unroll
        for (int rg = 0; rg < 4; ++rg)
            mr[m][rg] = fmaxf(fmaxf(acc[m][0][rg], acc[m][1][rg]),
                              fmaxf(acc[m][2][rg], acc[m][3][rg]));
#pragma unroll
    for (int d = 1; d < 16; d <<= 1)
#pragma unroll
        for (int m = 0; m < 4; ++m)
#pragma unroll
            for (int rg = 0; rg < 4; ++rg) mr[m][rg] = fmaxf(mr[m][rg], __shfl_xor(mr[m][rg], d));
    if ((lane & 15) == 0)
#pragma unroll
        for (int m = 0; m < 4; ++m)
#pragma unroll
            for (int rg = 0; rg < 4; ++rg) redm[wc][wr * 64 + m * 16 + rl + rg] = mr[m][rg];
    __syncthreads();
    float Mt[4][4];
#pragma unroll
    for (int m = 0; m < 4; ++m)
#pragma unroll
        for (int rg = 0; rg < 4; ++rg) {
            int row = wr * 64 + m * 16 + rl + rg;
            Mt[m][rg] = fmaxf(redm[0][row], redm[1][row]);
        }

    float sr[4][4] = {};
#pragma unroll
    for (int m = 0; m < 4; ++m)
#pragma unroll
        for (int n = 0; n < 4; ++n)
#pragma unroll
            for (int rg = 0; rg < 4; ++rg) {
                float e = __builtin_amdgcn_exp2f(acc[m][n][rg] - Mt[m][rg]);
                acc[m][n][rg] = e;
                sr[m][rg] += e;
            }
#pragma unroll
    for (int d = 1; d < 16; d <<= 1)
#pragma unroll
        for (int m = 0; m < 4; ++m)
#pragma unroll
            for (int rg = 0; rg < 4; ++rg) sr[m][rg] += __shfl_xor(sr[m][rg], d);
    if ((lane & 15) == 0)
#pragma unroll
        for (int m = 0; m < 4; ++m)
#pragma unroll
            for (int rg = 0; rg < 4; ++rg) reds[wc][wr * 64 + m * 16 + rl + rg] = sr[m][rg];
    __syncthreads();

    if (tid < 128) {
        float M = fmaxf(redm[0][tid], redm[1][tid]);
        float Z = reds[0][tid] + reds[1][tid];
        size_t o = ((size_t)bz * 8 + bx) * HW + m0 + tid;
        tmax[o] = M;
        tsum[o] = Z;
    }

    unsigned short* Sb = S + (size_t)bz * HW * HW;
#pragma unroll
    for (int m = 0; m < 4; ++m)
#pragma unroll
        for (int n = 0; n < 4; ++n) {
            int gm = m0 + wr * 64 + m * 16 + rl;
            int gn = n0 + wc * 64 + n * 16 + cl;
#pragma unroll
            for (int rg = 0; rg < 4; ++rg)
                Sb[(size_t)(gm + rg) * HW + gn] = f2bf(acc[m][n][rg]);
        }
}

// ---------------- Horner ratios for PV: r[jt][i] = exp2(Mt_jt - Mt_{jt+1}) (jt<7),
//                  r[7][i] = exp2(Mt_7 - Mrow) / Z
__global__ __launch_bounds__(256)
void rescale_kernel(const float* __restrict__ tmax, const float* __restrict__ tsum,
                    float* __restrict__ ratio) {
    int r = blockIdx.x * 256 + threadIdx.x;   // 16*1024 rows per half
    int b = r >> 10, i = r & 1023;
    const float* tm = tmax + (size_t)b * 8 * HW + i;
    const float* ts = tsum + (size_t)b * 8 * HW + i;
    float M = -1e30f;
#pragma unroll
    for (int jt = 0; jt < 8; ++jt) M = fmaxf(M, tm[(size_t)jt * HW]);
    float Z = 0.f;
#pragma unroll
    for (int jt = 0; jt < 8; ++jt) Z += ts[(size_t)jt * HW] * __builtin_amdgcn_exp2f(tm[(size_t)jt * HW] - M);
    float rZ = 1.0f / Z;
#pragma unroll
    for (int jt = 0; jt < 7; ++jt)
        ratio[((size_t)b * 8 + jt) * HW + i] =
            __builtin_amdgcn_exp2f(tm[(size_t)jt * HW] - tm[(size_t)(jt + 1) * HW]);
    ratio[((size_t)b * 8 + 7) * HW + i] = __builtin_amdgcn_exp2f(tm[(size_t)7 * HW] - M) * rZ;
}

// ---------------- PV GEMM (2-phase dbuf): single acc + Horner rescale per 128-col j-tile.
__global__ __launch_bounds__(256)
void pv_gemm(const unsigned short* __restrict__ A, const unsigned short* __restrict__ B,
             float* __restrict__ C, const float* __restrict__ bias,
             const float* __restrict__ resid, const float* __restrict__ ratio) {
    unsigned nx = gridDim.x, ny = gridDim.y;
    unsigned lin = blockIdx.x + nx * (blockIdx.y + ny * blockIdx.z);
    unsigned nwg = nx * ny * gridDim.z;
    unsigned work = (lin & 7) * (nwg >> 3) + (lin >> 3);
    unsigned bx = work % nx; work /= nx;
    unsigned by = work % ny;
    unsigned bz = work / ny;

    A += (size_t)bz * 512 * 1024;
    B += (size_t)bz * 1024 * 1024;
    int m0 = by * 128, n0 = bx * 128;

    __shared__ unsigned short lA[2][128 * 64];
    __shared__ unsigned short lB[2][128 * 64];

    int tid = threadIdx.x, lane = tid & 63;
    int wr = (tid >> 6) >> 1, wc = (tid >> 6) & 1;
    int cl = lane & 15;

    f32x4 acc[4][4] = {};

    int strow[4], stcol[4];
#pragma unroll
    for (int s = 0; s < 4; ++s) {
        int row = (s * 256 + tid) >> 3;
        int g = (tid & 7) ^ (row & 7);
        strow[s] = row;
        stcol[s] = g * 8;
    }

    auto stage = [&](int buf, int k0) {
#pragma unroll
        for (int s = 0; s < 4; ++s) {
            GLD16(A + (size_t)(m0 + strow[s]) * 1024 + k0 + stcol[s], &lA[buf][(size_t)(s * 256 + tid) * 8]);
            GLD16(B + (size_t)(n0 + strow[s]) * 1024 + k0 + stcol[s], &lB[buf][(size_t)(s * 256 + tid) * 8]);
        }
    };

    const float* rbase = ratio + (size_t)bz * 8 * HW + n0 + wc * 64 + cl;

    stage(0, 0);
    __syncthreads();
    int cur = 0;
    float r0 = 0.f, r1 = 0.f, r2 = 0.f, r3 = 0.f;
    for (int t = 0; t < 16; ++t) {
        if (t + 1 < 16) stage(cur ^ 1, (t + 1) << 6);
        if (!(t & 1)) {   // issue this j-tile's ratio loads early; used after the barrier
            int jt = t >> 1;
            r0 = rbase[(size_t)jt * HW + 0];
            r1 = rbase[(size_t)jt * HW + 16];
            r2 = rbase[(size_t)jt * HW + 32];
            r3 = rbase[(size_t)jt * HW + 48];
        }
        const char* pa = (const char*)lA[cur];
        const char* pb = (const char*)lB[cur];
#pragma unroll
        for (int kk = 0; kk < 64; kk += 32) {
            bf16x8 af[4], bfr[4];
#pragma unroll
            for (int m = 0; m < 4; ++m) {
                int row = wr * 64 + m * 16 + (lane & 15);
                int off = (row * 128 + (kk + (lane >> 4) * 8) * 2) ^ ((row & 7) << 4);
                af[m] = *(const bf16x8*)(pa + off);
            }
#pragma unroll
            for (int n = 0; n < 4; ++n) {
                int row = wc * 64 + n * 16 + (lane & 15);
                int off = (row * 128 + (kk + (lane >> 4) * 8) * 2) ^ ((row & 7) << 4);
                bfr[n] = *(const bf16x8*)(pb + off);
            }
#pragma unroll
            for (int m = 0; m < 4; ++m)
#pragma unroll
                for (int n = 0; n < 4; ++n)
                    acc[m][n] = __builtin_amdgcn_mfma_f32_16x16x32_bf16(af[m], bfr[n], acc[m][n], 0, 0, 0);
        }
        __syncthreads();
        cur ^= 1;
        if (t & 1) {   // end of 128-col j-tile: Horner fold (register-only)
#pragma unroll
            for (int m = 0; m < 4; ++m) {
                acc[m][0] *= r0;
                acc[m][1] *= r1;
                acc[m][2] *= r2;
                acc[m][3] *= r3;
            }
        }
    }

    int rl = (lane >> 4) * 4;
    float* Cf = C + (size_t)bz * 512 * 1024;
    const float* Rs = resid + (size_t)bz * 512 * 1024;
#pragma unroll
    for (int m = 0; m < 4; ++m)
#pragma unroll
        for (int n = 0; n < 4; ++n) {
            int gm = m0 + wr * 64 + m * 16 + rl;
            int gn = n0 + wc * 64 + n * 16 + cl;
#pragma unroll
            for (int rg = 0; rg < 4; ++rg) {
                size_t off = (size_t)(gm + rg) * 1024 + gn;
                Cf[off] = acc[m][n][rg] + bias[gm + rg] + Rs[off];
            }
        }
}

// ---------------- launch
extern "C" void kernel_launch(void* const* d_in, const int* in_sizes, int n_in,
                              void* d_out, int out_size, void* d_ws, size_t ws_size,
                              hipStream_t stream) {
    const float* x      = (const float*)d_in[0];
    const float* gamma  = (const float*)d_in[1];
    const float* beta   = (const float*)d_in[2];
    const float* qkv_w  = (const float*)d_in[3];
    const float* qkv_b  = (const float*)d_in[4];
    const float* out_w  = (const float*)d_in[5];
    const float* out_b  = (const float*)d_in[6];

    char* ws = (char*)d_ws;
    unsigned short* xnT  = (unsigned short*)ws;                   // 32 MB
    unsigned short* vpr  = (unsigned short*)(ws + 33554432);      // 32 MB
    unsigned short* SP   = (unsigned short*)(ws + 67108864);      // 32 MB (half-batch E)
    unsigned short* wqkT = (unsigned short*)(ws + 100663296);     // 512 KB
    unsigned short* w2   = (unsigned short*)(ws + 101187584);     // 512 KB (= wqkT + 262144 elems)
    float* gvec          = (float*)(ws + 101711872);
    float* bias2         = (float*)(ws + 101713920);
    float* meanp         = (float*)(ws + 101715968);
    float* rstdp         = (float*)(ws + 101716992);
    float* tmaxp         = (float*)(ws + 101718016);              // 1 MB
    float* tsump         = (float*)(ws + 102766592);              // 1 MB
    float* ratiop        = (float*)(ws + 103815168);              // 512 KB (per half)

    // transient weight-prep slots in the SP region (dead before scores_gemm writes SP)
    // slot0: wqT, slot1: wvT, slot2: wkT, slot3: owb  (each 262144 elems)
    unsigned short* slot0 = SP;
    unsigned short* owb   = SP + 786432;

    // T1 parked in d_out[32MB..64MB]; PV half-0 writes d_out[0..32MB] only.
    unsigned short* T1 = (unsigned short*)((char*)d_out + 33554432);
    float* outF = (float*)d_out;

    const float* wk_f = qkv_w + (size_t)512 * CD;

    gn_stats<<<256, 256, 0, stream>>>(x, meanp, rstdp);
    gn_norm_t<<<dim3(16, 8, 32), 256, 0, stream>>>(x, meanp, rstdp, gamma, beta, xnT);

    tpose3_bf16<<<dim3(8, 8, 3), 256, 0, stream>>>(qkv_w, slot0);  // wq->s0, wk->s2, wv->s1
    cvt_bf16<<<256, 256, 0, stream>>>(out_w, owb);                 // -> s3
    gvec_kernel<<<8, 256, 0, stream>>>(wk_f, qkv_b, gvec);
    bias2_kernel<<<128, 256, 0, stream>>>(out_w, qkv_b + 1024, bias2);

    // z=0: wqkT = wkT . wqT^T ; z=1: w2 = owb . wvT^T   (A-pair s2,s3; B-pair s0,s1)
    gemm_bt<3><<<dim3(4, 4, 2), 256, 0, stream>>>(slot0 + 524288, slot0, wqkT, nullptr,
        512, 512, 512, 262144, 262144, 262144);

    // T1[b,i,d] = xnT[b,i,:] . wqkT[d,:] + g[d]
    gemm_bt<0><<<dim3(4, 8, 32), 256, 0, stream>>>(xnT, wqkT, T1, gvec,
        1024, 512, 512, 1024LL * 512, 0, 1024LL * 512);
    // vpr[b,o,i] = w2[o,:] . xnT[b,i,:] + bias2[o]
    gemm_bt<1><<<dim3(8, 4, 32), 256, 0, stream>>>(w2, xnT, vpr, bias2,
        512, 1024, 512, 0, 1024LL * 512, 512LL * 1024);

    for (int h = 0; h < 2; ++h) {
        const unsigned short* T1h = T1 + (size_t)h * 16 * 1024 * 512;
        const unsigned short* xh  = xnT + (size_t)h * 16 * 1024 * 512;
        float* tmaxh = tmaxp + (size_t)h * 16 * 8 * 1024;
        float* tsumh = tsump + (size_t)h * 16 * 8 * 1024;

        scores_gemm<<<dim3(8, 8, 16), 256, 0, stream>>>(T1h, xh, SP, tmaxh, tsumh);
        rescale_kernel<<<64, 256, 0, stream>>>(tmaxh, tsumh, ratiop);
        pv_gemm<<<dim3(8, 4, 16), 256, 0, stream>>>(
            vpr + (size_t)h * 16 * 512 * 1024, SP,
            outF + (size_t)h * 16 * 512 * 1024, out_b,
            x + (size_t)h * 16 * 512 * 1024, ratiop);
    }
    (void)in_sizes; (void)n_in; (void)out_size; (void)ws_size;
}

// Round 16
// 220.642 us; speedup vs baseline: 1.2536x; 1.0100x over previous
//
#include <hip/hip_runtime.h>

#define HW 1024
#define CD 512

typedef __bf16 bf16x8 __attribute__((ext_vector_type(8)));
typedef float f32x4 __attribute__((ext_vector_type(4)));

__device__ __forceinline__ unsigned short f2bf(float f) {
    unsigned int u = __float_as_uint(f);
    u += 0x7fff + ((u >> 16) & 1);   // RNE
    return (unsigned short)(u >> 16);
}
__device__ __forceinline__ float bf2f(unsigned short h) {
    return __uint_as_float((unsigned)h << 16);
}

#define AS1(p) ((__attribute__((address_space(1))) void*)(p))
#define AS3(p) ((__attribute__((address_space(3))) void*)(p))
#define GLD16(gp, lp) __builtin_amdgcn_global_load_lds(AS1(gp), AS3(lp), 16, 0, 0)
#define WAITVM(n) do { asm volatile("s_waitcnt vmcnt(" #n ")" ::: "memory"); \
                       __builtin_amdgcn_sched_barrier(0); } while (0)

// ---------------- GroupNorm stats: one block per (b,g)
__global__ __launch_bounds__(256)
void gn_stats(const float* __restrict__ x, float* __restrict__ mean, float* __restrict__ rstd) {
    int bg = blockIdx.x;
    const float4* p4 = (const float4*)(x + (size_t)bg * 65536);
    int tid = threadIdx.x;
    float s = 0.f, ss = 0.f;
#pragma unroll 8
    for (int it = 0; it < 64; ++it) {
        float4 v = p4[tid + it * 256];
        s  += v.x + v.y + v.z + v.w;
        ss += v.x * v.x + v.y * v.y + v.z * v.z + v.w * v.w;
    }
#pragma unroll
    for (int d = 32; d > 0; d >>= 1) { s += __shfl_down(s, d); ss += __shfl_down(ss, d); }
    __shared__ float ls[4], lss[4];
    if ((tid & 63) == 0) { ls[tid >> 6] = s; lss[tid >> 6] = ss; }
    __syncthreads();
    if (tid == 0) {
        float S = ls[0] + ls[1] + ls[2] + ls[3];
        float SS = lss[0] + lss[1] + lss[2] + lss[3];
        float m = S * (1.f / 65536.f);
        float v = SS * (1.f / 65536.f) - m * m;
        mean[bg] = m;
        rstd[bg] = rsqrtf(v + 1e-5f);
    }
}

// ---------------- normalize + transpose: x[b,c,hw] f32 -> xnT[b,hw,c] bf16 (pad 67)
__global__ __launch_bounds__(256)
void gn_norm_t(const float* __restrict__ x, const float* __restrict__ mean, const float* __restrict__ rstd,
               const float* __restrict__ gamma, const float* __restrict__ beta,
               unsigned short* __restrict__ xnT) {
    __shared__ unsigned short tile[64][67];
    int i0 = blockIdx.x * 64, c0 = blockIdx.y * 64, b = blockIdx.z;
    float m = mean[b * 8 + blockIdx.y];
    float r = rstd[b * 8 + blockIdx.y];
    int tid = threadIdx.x;
    int tr = tid >> 4, tc = (tid & 15) * 4;
    const float* xb = x + ((size_t)b * CD + c0) * HW + i0;
#pragma unroll
    for (int p = 0; p < 4; ++p) {
        int c = tr + p * 16;
        float g = gamma[c0 + c] * r;
        float bb = beta[c0 + c] - m * g;
        float4 v = *(const float4*)(xb + (size_t)c * HW + tc);
        tile[c][tc + 0] = f2bf(v.x * g + bb);
        tile[c][tc + 1] = f2bf(v.y * g + bb);
        tile[c][tc + 2] = f2bf(v.z * g + bb);
        tile[c][tc + 3] = f2bf(v.w * g + bb);
    }
    __syncthreads();
    unsigned short* ob = xnT + ((size_t)b * HW + i0) * CD + c0;
#pragma unroll
    for (int p = 0; p < 4; ++p) {
        int ir = tr + p * 16;
        ushort4 u;
        u.x = tile[tc + 0][ir];
        u.y = tile[tc + 1][ir];
        u.z = tile[tc + 2][ir];
        u.w = tile[tc + 3][ir];
        *(ushort4*)(ob + (size_t)ir * CD + tc) = u;
    }
}

// ---------------- transpose + cvt x3: qkv_w row-blocks -> bf16 transposed (pad 67)
__global__ __launch_bounds__(256)
void tpose3_bf16(const float* __restrict__ qkv_w, unsigned short* __restrict__ dst0) {
    __shared__ unsigned short tile[64][67];
    const int zmap[3] = {0, 2, 1};
    const float* src = qkv_w + (size_t)blockIdx.z * CD * CD;
    unsigned short* dst = dst0 + (size_t)zmap[blockIdx.z] * CD * CD;
    int i0 = blockIdx.x * 64, c0 = blockIdx.y * 64;
    int tid = threadIdx.x;
    int tr = tid >> 4, tc = (tid & 15) * 4;
#pragma unroll
    for (int p = 0; p < 4; ++p) {
        int r = tr + p * 16;
        float4 v = *(const float4*)(src + (size_t)(i0 + r) * CD + c0 + tc);
        tile[r][tc + 0] = f2bf(v.x);
        tile[r][tc + 1] = f2bf(v.y);
        tile[r][tc + 2] = f2bf(v.z);
        tile[r][tc + 3] = f2bf(v.w);
    }
    __syncthreads();
#pragma unroll
    for (int p = 0; p < 4; ++p) {
        int ir = tr + p * 16;
        ushort4 u;
        u.x = tile[tc + 0][ir];
        u.y = tile[tc + 1][ir];
        u.z = tile[tc + 2][ir];
        u.w = tile[tc + 3][ir];
        *(ushort4*)(dst + (size_t)(c0 + ir) * CD + i0 + tc) = u;
    }
}

// ---------------- f32 -> bf16 convert
__global__ __launch_bounds__(256)
void cvt_bf16(const float* __restrict__ src, unsigned short* __restrict__ dst) {
    int i = blockIdx.x * 256 + threadIdx.x;
    float4 v = ((const float4*)src)[i];
    ushort4 u;
    u.x = f2bf(v.x); u.y = f2bf(v.y); u.z = f2bf(v.z); u.w = f2bf(v.w);
    ((ushort4*)dst)[i] = u;
}

// ---------------- g[d] = sum_o wk[o][d] * bq[o]
__global__ __launch_bounds__(256)
void gvec_kernel(const float* __restrict__ wk, const float* __restrict__ bq,
                 float* __restrict__ g) {
    __shared__ float red[4][64];
    int d = blockIdx.x * 64 + (threadIdx.x & 63);
    int os = threadIdx.x >> 6;
    float acc = 0.f;
    for (int o = os * 128; o < os * 128 + 128; ++o)
        acc += wk[(size_t)o * CD + d] * bq[o];
    red[os][threadIdx.x & 63] = acc;
    __syncthreads();
    if (threadIdx.x < 64)
        g[blockIdx.x * 64 + threadIdx.x] = red[0][threadIdx.x] + red[1][threadIdx.x] +
                                           red[2][threadIdx.x] + red[3][threadIdx.x];
}

// ---------------- bias2[o] = sum_t out_w[o][t] * bv[t]
__global__ __launch_bounds__(256)
void bias2_kernel(const float* __restrict__ out_w, const float* __restrict__ bv,
                  float* __restrict__ bias2) {
    int wid = threadIdx.x >> 6, lane = threadIdx.x & 63;
    int o = blockIdx.x * 4 + wid;
    float acc = 0.f;
#pragma unroll
    for (int t = 0; t < 512; t += 64)
        acc += out_w[(size_t)o * CD + t + lane] * bv[t + lane];
#pragma unroll
    for (int d = 32; d > 0; d >>= 1) acc += __shfl_down(acc, d);
    if (lane == 0) bias2[o] = acc;
}

// ======== gemm8: 256x256 tile, BK=64, counted-vmcnt 2-deep pipeline ==================
// 512 thr, 8 waves (2M x 4N), per-wave 128x64 (acc[8][4]). LDS 2 x 64KB dbuf.
// Per iter: vmcnt(8) [tile t done, t+1 in flight] -> s_barrier -> frags+MFMA ->
// s_barrier -> stage(t+2). vmcnt(0) only on the last iteration.
// EPI 0: bf16 + bias[col] | 1: bf16 + bias[row]
template<int EPI>
__global__ __launch_bounds__(512, 2)
void gemm8(const unsigned short* __restrict__ A, const unsigned short* __restrict__ B,
           unsigned short* __restrict__ C, const float* __restrict__ bias,
           int M, int N, int K, long long sA, long long sB, long long sC) {
    unsigned nx = gridDim.x, ny = gridDim.y;
    unsigned lin = blockIdx.x + nx * (blockIdx.y + ny * blockIdx.z);
    unsigned nwg = nx * ny * gridDim.z;
    unsigned work = (lin & 7) * (nwg >> 3) + (lin >> 3);
    unsigned bx = work % nx; work /= nx;
    unsigned by = work % ny;
    unsigned bz = work / ny;

    A += (size_t)bz * sA;
    B += (size_t)bz * sB;
    int m0 = by * 256, n0 = bx * 256;

    __shared__ unsigned short lA[2][256 * 64];
    __shared__ unsigned short lB[2][256 * 64];

    int tid = threadIdx.x, lane = tid & 63, wid = tid >> 6;
    int wr = wid >> 2, wc = wid & 3;     // 2M x 4N waves; per-wave 128 rows x 64 cols

    f32x4 acc[8][4] = {};

    // staging map: 2048 granules (16B) per matrix tile; idx = s*512 + tid (lane stride 16B)
    int strow[4], stcol[4];
#pragma unroll
    for (int s = 0; s < 4; ++s) {
        int idx = s * 512 + tid;
        strow[s] = idx >> 3;
        stcol[s] = ((idx & 7) ^ (strow[s] & 7)) * 8;
    }

    auto stage = [&](int buf, int kt) {
        int k0 = kt << 6;
#pragma unroll
        for (int s = 0; s < 4; ++s)
            GLD16(A + (size_t)(m0 + strow[s]) * K + k0 + stcol[s], &lA[buf][(size_t)(s * 512 + tid) * 8]);
#pragma unroll
        for (int s = 0; s < 4; ++s)
            GLD16(B + (size_t)(n0 + strow[s]) * K + k0 + stcol[s], &lB[buf][(size_t)(s * 512 + tid) * 8]);
    };

    int NT = K >> 6;
    stage(0, 0);
    if (NT > 1) stage(1, 1);

    for (int t = 0; t < NT; ++t) {
        if (t < NT - 1) WAITVM(8); else WAITVM(0);
        __builtin_amdgcn_s_barrier();
        const char* pa = (const char*)lA[t & 1];
        const char* pb = (const char*)lB[t & 1];
        __builtin_amdgcn_s_setprio(1);
#pragma unroll
        for (int kk = 0; kk < 64; kk += 32) {
            int koff = (kk + (lane >> 4) * 8) * 2;
            bf16x8 af[8], bfr[4];
#pragma unroll
            for (int m = 0; m < 8; ++m) {
                int row = wr * 128 + m * 16 + (lane & 15);
                af[m] = *(const bf16x8*)(pa + ((row * 128 + koff) ^ ((row & 7) << 4)));
            }
#pragma unroll
            for (int n = 0; n < 4; ++n) {
                int row = wc * 64 + n * 16 + (lane & 15);
                bfr[n] = *(const bf16x8*)(pb + ((row * 128 + koff) ^ ((row & 7) << 4)));
            }
#pragma unroll
            for (int m = 0; m < 8; ++m)
#pragma unroll
                for (int n = 0; n < 4; ++n)
                    acc[m][n] = __builtin_amdgcn_mfma_f32_16x16x32_bf16(af[m], bfr[n], acc[m][n], 0, 0, 0);
        }
        __builtin_amdgcn_s_setprio(0);
        __builtin_amdgcn_s_barrier();
        if (t + 2 < NT) stage(t & 1, t + 2);
    }

    int rl = (lane >> 4) * 4;
    int cl = lane & 15;
    unsigned short* Cb = C + (size_t)bz * sC;
#pragma unroll
    for (int m = 0; m < 8; ++m)
#pragma unroll
        for (int n = 0; n < 4; ++n) {
            int gm = m0 + wr * 128 + m * 16 + rl;
            int gn = n0 + wc * 64 + n * 16 + cl;
#pragma unroll
            for (int rg = 0; rg < 4; ++rg) {
                float v = acc[m][n][rg];
                if (EPI == 0) v += bias[gn];
                if (EPI == 1) v += bias[gm + rg];
                Cb[(size_t)(gm + rg) * N + gn] = f2bf(v);
            }
        }
}

// ---------------- generic bf16 GEMM (128x128, 2-phase dbuf) — weight-pair GEMM
template<int EPI>
__global__ __launch_bounds__(256, 2)
void gemm_bt(const unsigned short* __restrict__ A, const unsigned short* __restrict__ B,
             void* __restrict__ Cv, const float* __restrict__ bias,
             int M, int N, int K, long long sA, long long sB, long long sC) {
    unsigned nx = gridDim.x, ny = gridDim.y;
    unsigned lin = blockIdx.x + nx * (blockIdx.y + ny * blockIdx.z);
    unsigned nwg = nx * ny * gridDim.z;
    unsigned work = (lin & 7) * (nwg >> 3) + (lin >> 3);
    unsigned bx = work % nx; work /= nx;
    unsigned by = work % ny;
    unsigned bz = work / ny;

    A += (size_t)bz * sA;
    B += (size_t)bz * sB;
    int m0 = by * 128, n0 = bx * 128;

    __shared__ unsigned short lA[2][128 * 64];
    __shared__ unsigned short lB[2][128 * 64];

    int tid = threadIdx.x;
    int lane = tid & 63;
    int wr = (tid >> 6) >> 1, wc = (tid >> 6) & 1;

    f32x4 acc[4][4] = {};

    int strow[4], stcol[4];
#pragma unroll
    for (int s = 0; s < 4; ++s) {
        int row = (s * 256 + tid) >> 3;
        int g = (tid & 7) ^ (row & 7);
        strow[s] = row;
        stcol[s] = g * 8;
    }

    auto stage = [&](int buf, int k0) {
#pragma unroll
        for (int s = 0; s < 4; ++s) {
            GLD16(A + (size_t)(m0 + strow[s]) * K + k0 + stcol[s], &lA[buf][(size_t)(s * 256 + tid) * 8]);
            GLD16(B + (size_t)(n0 + strow[s]) * K + k0 + stcol[s], &lB[buf][(size_t)(s * 256 + tid) * 8]);
        }
    };

    int NT = K >> 6;
    stage(0, 0);
    __syncthreads();
    int cur = 0;
    for (int t = 0; t < NT; ++t) {
        if (t + 1 < NT) stage(cur ^ 1, (t + 1) << 6);
        const char* pa = (const char*)lA[cur];
        const char* pb = (const char*)lB[cur];
#pragma unroll
        for (int kk = 0; kk < 64; kk += 32) {
            bf16x8 af[4], bfr[4];
#pragma unroll
            for (int m = 0; m < 4; ++m) {
                int row = wr * 64 + m * 16 + (lane & 15);
                int off = (row * 128 + (kk + (lane >> 4) * 8) * 2) ^ ((row & 7) << 4);
                af[m] = *(const bf16x8*)(pa + off);
            }
#pragma unroll
            for (int n = 0; n < 4; ++n) {
                int row = wc * 64 + n * 16 + (lane & 15);
                int off = (row * 128 + (kk + (lane >> 4) * 8) * 2) ^ ((row & 7) << 4);
                bfr[n] = *(const bf16x8*)(pb + off);
            }
#pragma unroll
            for (int m = 0; m < 4; ++m)
#pragma unroll
                for (int n = 0; n < 4; ++n)
                    acc[m][n] = __builtin_amdgcn_mfma_f32_16x16x32_bf16(af[m], bfr[n], acc[m][n], 0, 0, 0);
        }
        __syncthreads();
        cur ^= 1;
    }

    int rl = (lane >> 4) * 4;
    int cl = lane & 15;
    unsigned short* Cb = (unsigned short*)Cv + (size_t)bz * sC;
#pragma unroll
    for (int m = 0; m < 4; ++m)
#pragma unroll
        for (int n = 0; n < 4; ++n) {
            int gm = m0 + wr * 64 + m * 16 + rl;
            int gn = n0 + wc * 64 + n * 16 + cl;
#pragma unroll
            for (int rg = 0; rg < 4; ++rg) {
                float v = acc[m][n][rg];
                if (EPI == 0) v += bias[gn];
                if (EPI == 1) v += bias[gm + rg];
                Cb[(size_t)(gm + rg) * N + gn] = f2bf(v);
            }
        }
}

// ---------------- scores GEMM (2-phase dbuf): stores E = exp2(t - Mtile) bf16 + tile stats
__global__ __launch_bounds__(256, 2)
void scores_gemm(const unsigned short* __restrict__ T1, const unsigned short* __restrict__ xnT,
                 unsigned short* __restrict__ S, float* __restrict__ tmax, float* __restrict__ tsum) {
    unsigned nx = gridDim.x, ny = gridDim.y;
    unsigned lin = blockIdx.x + nx * (blockIdx.y + ny * blockIdx.z);
    unsigned nwg = nx * ny * gridDim.z;
    unsigned work = (lin & 7) * (nwg >> 3) + (lin >> 3);
    unsigned bx = work % nx; work /= nx;
    unsigned by = work % ny;
    unsigned bz = work / ny;

    const unsigned short* Ab = T1 + (size_t)bz * HW * CD;
    const unsigned short* Bb = xnT + (size_t)bz * HW * CD;
    int m0 = by * 128, n0 = bx * 128;

    __shared__ unsigned short lA[2][128 * 64];
    __shared__ unsigned short lB[2][128 * 64];
    __shared__ float redm[2][128];
    __shared__ float reds[2][128];

    int tid = threadIdx.x, lane = tid & 63;
    int wr = (tid >> 6) >> 1, wc = (tid >> 6) & 1;

    f32x4 acc[4][4] = {};
    int strow[4], stcol[4];
#pragma unroll
    for (int s = 0; s < 4; ++s) {
        int row = (s * 256 + tid) >> 3;
        int g = (tid & 7) ^ (row & 7);
        strow[s] = row;
        stcol[s] = g * 8;
    }

    auto stage = [&](int buf, int k0) {
#pragma unroll
        for (int s = 0; s < 4; ++s) {
            GLD16(Ab + (size_t)(m0 + strow[s]) * CD + k0 + stcol[s], &lA[buf][(size_t)(s * 256 + tid) * 8]);
            GLD16(Bb + (size_t)(n0 + strow[s]) * CD + k0 + stcol[s], &lB[buf][(size_t)(s * 256 + tid) * 8]);
        }
    };

    stage(0, 0);
    __syncthreads();
    int cur = 0;
    for (int t = 0; t < 8; ++t) {
        if (t < 7) stage(cur ^ 1, (t + 1) << 6);
        const char* pa = (const char*)lA[cur];
        const char* pb = (const char*)lB[cur];
#pragma unroll
        for (int kk = 0; kk < 64; kk += 32) {
            bf16x8 af[4], bfr[4];
#pragma unroll
            for (int m = 0; m < 4; ++m) {
                int row = wr * 64 + m * 16 + (lane & 15);
                int off = (row * 128 + (kk + (lane >> 4) * 8) * 2) ^ ((row & 7) << 4);
                af[m] = *(const bf16x8*)(pa + off);
            }
#pragma unroll
            for (int n = 0; n < 4; ++n) {
                int row = wc * 64 + n * 16 + (lane & 15);
                int off = (row * 128 + (kk + (lane >> 4) * 8) * 2) ^ ((row & 7) << 4);
                bfr[n] = *(const bf16x8*)(pb + off);
            }
#pragma unroll
            for (int m = 0; m < 4; ++m)
#pragma unroll
                for (int n = 0; n < 4; ++n)
                    acc[m][n] = __builtin_amdgcn_mfma_f32_16x16x32_bf16(af[m], bfr[n], acc[m][n], 0, 0, 0);
        }
        __syncthreads();
        cur ^= 1;
    }

    const float SL2E = 0.044194173824159216f * 1.4426950408889634f;
#pragma unroll
    for (int m = 0; m < 4; ++m)
#pragma unroll
        for (int n = 0; n < 4; ++n) acc[m][n] *= SL2E;

    int rl = (lane >> 4) * 4;
    int cl = lane & 15;

    float mr[4][4];
#pragma unroll
    for (int m = 0; m < 4; ++m)
#pragma unroll
        for (int rg = 0; rg < 4; ++rg)
            mr[m][rg] = fmaxf(fmaxf(acc[m][0][rg], acc[m][1][rg]),
                              fmaxf(acc[m][2][rg], acc[m][3][rg]));
#pragma unroll
    for (int d = 1; d < 16; d <<= 1)
#pragma unroll
        for (int m = 0; m < 4; ++m)
#pragma unroll
            for (int rg = 0; rg < 4; ++rg) mr[m][rg] = fmaxf(mr[m][rg], __shfl_xor(mr[m][rg], d));
    if ((lane & 15) == 0)
#pragma unroll
        for (int m = 0; m < 4; ++m)
#pragma unroll
            for (int rg = 0; rg < 4; ++rg) redm[wc][wr * 64 + m * 16 + rl + rg] = mr[m][rg];
    __syncthreads();
    float Mt[4][4];
#pragma unroll
    for (int m = 0; m < 4; ++m)
#pragma unroll
        for (int rg = 0; rg < 4; ++rg) {
            int row = wr * 64 + m * 16 + rl + rg;
            Mt[m][rg] = fmaxf(redm[0][row], redm[1][row]);
        }

    float sr[4][4] = {};
#pragma unroll
    for (int m = 0; m < 4; ++m)
#pragma unroll
        for (int n = 0; n < 4; ++n)
#pragma unroll
            for (int rg = 0; rg < 4; ++rg) {
                float e = __builtin_amdgcn_exp2f(acc[m][n][rg] - Mt[m][rg]);
                acc[m][n][rg] = e;
                sr[m][rg] += e;
            }
#pragma unroll
    for (int d = 1; d < 16; d <<= 1)
#pragma unroll
        for (int m = 0; m < 4; ++m)
#pragma unroll
            for (int rg = 0; rg < 4; ++rg) sr[m][rg] += __shfl_xor(sr[m][rg], d);
    if ((lane & 15) == 0)
#pragma unroll
        for (int m = 0; m < 4; ++m)
#pragma unroll
            for (int rg = 0; rg < 4; ++rg) reds[wc][wr * 64 + m * 16 + rl + rg] = sr[m][rg];
    __syncthreads();

    if (tid < 128) {
        float M = fmaxf(redm[0][tid], redm[1][tid]);
        float Z = reds[0][tid] + reds[1][tid];
        size_t o = ((size_t)bz * 8 + bx) * HW + m0 + tid;
        tmax[o] = M;
        tsum[o] = Z;
    }

    unsigned short* Sb = S + (size_t)bz * HW * HW;
#pragma unroll
    for (int m = 0; m < 4; ++m)
#pragma unroll
        for (int n = 0; n < 4; ++n) {
            int gm = m0 + wr * 64 + m * 16 + rl;
            int gn = n0 + wc * 64 + n * 16 + cl;
#pragma unroll
            for (int rg = 0; rg < 4; ++rg)
                Sb[(size_t)(gm + rg) * HW + gn] = f2bf(acc[m][n][rg]);
        }
}

// ---------------- Horner ratios for PV
__global__ __launch_bounds__(256)
void rescale_kernel(const float* __restrict__ tmax, const float* __restrict__ tsum,
                    float* __restrict__ ratio) {
    int r = blockIdx.x * 256 + threadIdx.x;   // 16*1024 rows per half
    int b = r >> 10, i = r & 1023;
    const float* tm = tmax + (size_t)b * 8 * HW + i;
    const float* ts = tsum + (size_t)b * 8 * HW + i;
    float M = -1e30f;
#pragma unroll
    for (int jt = 0; jt < 8; ++jt) M = fmaxf(M, tm[(size_t)jt * HW]);
    float Z = 0.f;
#pragma unroll
    for (int jt = 0; jt < 8; ++jt) Z += ts[(size_t)jt * HW] * __builtin_amdgcn_exp2f(tm[(size_t)jt * HW] - M);
    float rZ = 1.0f / Z;
#pragma unroll
    for (int jt = 0; jt < 7; ++jt)
        ratio[((size_t)b * 8 + jt) * HW + i] =
            __builtin_amdgcn_exp2f(tm[(size_t)jt * HW] - tm[(size_t)(jt + 1) * HW]);
    ratio[((size_t)b * 8 + 7) * HW + i] = __builtin_amdgcn_exp2f(tm[(size_t)7 * HW] - M) * rZ;
}

// ---------------- PV GEMM (2-phase dbuf): single acc + Horner rescale per 128-col j-tile.
__global__ __launch_bounds__(256)
void pv_gemm(const unsigned short* __restrict__ A, const unsigned short* __restrict__ B,
             float* __restrict__ C, const float* __restrict__ bias,
             const float* __restrict__ resid, const float* __restrict__ ratio) {
    unsigned nx = gridDim.x, ny = gridDim.y;
    unsigned lin = blockIdx.x + nx * (blockIdx.y + ny * blockIdx.z);
    unsigned nwg = nx * ny * gridDim.z;
    unsigned work = (lin & 7) * (nwg >> 3) + (lin >> 3);
    unsigned bx = work % nx; work /= nx;
    unsigned by = work % ny;
    unsigned bz = work / ny;

    A += (size_t)bz * 512 * 1024;
    B += (size_t)bz * 1024 * 1024;
    int m0 = by * 128, n0 = bx * 128;

    __shared__ unsigned short lA[2][128 * 64];
    __shared__ unsigned short lB[2][128 * 64];

    int tid = threadIdx.x, lane = tid & 63;
    int wr = (tid >> 6) >> 1, wc = (tid >> 6) & 1;
    int cl = lane & 15;

    f32x4 acc[4][4] = {};

    int strow[4], stcol[4];
#pragma unroll
    for (int s = 0; s < 4; ++s) {
        int row = (s * 256 + tid) >> 3;
        int g = (tid & 7) ^ (row & 7);
        strow[s] = row;
        stcol[s] = g * 8;
    }

    auto stage = [&](int buf, int k0) {
#pragma unroll
        for (int s = 0; s < 4; ++s) {
            GLD16(A + (size_t)(m0 + strow[s]) * 1024 + k0 + stcol[s], &lA[buf][(size_t)(s * 256 + tid) * 8]);
            GLD16(B + (size_t)(n0 + strow[s]) * 1024 + k0 + stcol[s], &lB[buf][(size_t)(s * 256 + tid) * 8]);
        }
    };

    const float* rbase = ratio + (size_t)bz * 8 * HW + n0 + wc * 64 + cl;

    stage(0, 0);
    __syncthreads();
    int cur = 0;
    float r0 = 0.f, r1 = 0.f, r2 = 0.f, r3 = 0.f;
    for (int t = 0; t < 16; ++t) {
        if (t + 1 < 16) stage(cur ^ 1, (t + 1) << 6);
        if (!(t & 1)) {
            int jt = t >> 1;
            r0 = rbase[(size_t)jt * HW + 0];
            r1 = rbase[(size_t)jt * HW + 16];
            r2 = rbase[(size_t)jt * HW + 32];
            r3 = rbase[(size_t)jt * HW + 48];
        }
        const char* pa = (const char*)lA[cur];
        const char* pb = (const char*)lB[cur];
#pragma unroll
        for (int kk = 0; kk < 64; kk += 32) {
            bf16x8 af[4], bfr[4];
#pragma unroll
            for (int m = 0; m < 4; ++m) {
                int row = wr * 64 + m * 16 + (lane & 15);
                int off = (row * 128 + (kk + (lane >> 4) * 8) * 2) ^ ((row & 7) << 4);
                af[m] = *(const bf16x8*)(pa + off);
            }
#pragma unroll
            for (int n = 0; n < 4; ++n) {
                int row = wc * 64 + n * 16 + (lane & 15);
                int off = (row * 128 + (kk + (lane >> 4) * 8) * 2) ^ ((row & 7) << 4);
                bfr[n] = *(const bf16x8*)(pb + off);
            }
#pragma unroll
            for (int m = 0; m < 4; ++m)
#pragma unroll
                for (int n = 0; n < 4; ++n)
                    acc[m][n] = __builtin_amdgcn_mfma_f32_16x16x32_bf16(af[m], bfr[n], acc[m][n], 0, 0, 0);
        }
        __syncthreads();
        cur ^= 1;
        if (t & 1) {
#pragma unroll
            for (int m = 0; m < 4; ++m) {
                acc[m][0] *= r0;
                acc[m][1] *= r1;
                acc[m][2] *= r2;
                acc[m][3] *= r3;
            }
        }
    }

    int rl = (lane >> 4) * 4;
    float* Cf = C + (size_t)bz * 512 * 1024;
    const float* Rs = resid + (size_t)bz * 512 * 1024;
#pragma unroll
    for (int m = 0; m < 4; ++m)
#pragma unroll
        for (int n = 0; n < 4; ++n) {
            int gm = m0 + wr * 64 + m * 16 + rl;
            int gn = n0 + wc * 64 + n * 16 + cl;
#pragma unroll
            for (int rg = 0; rg < 4; ++rg) {
                size_t off = (size_t)(gm + rg) * 1024 + gn;
                Cf[off] = acc[m][n][rg] + bias[gm + rg] + Rs[off];
            }
        }
}

// ---------------- launch
extern "C" void kernel_launch(void* const* d_in, const int* in_sizes, int n_in,
                              void* d_out, int out_size, void* d_ws, size_t ws_size,
                              hipStream_t stream) {
    const float* x      = (const float*)d_in[0];
    const float* gamma  = (const float*)d_in[1];
    const float* beta   = (const float*)d_in[2];
    const float* qkv_w  = (const float*)d_in[3];
    const float* qkv_b  = (const float*)d_in[4];
    const float* out_w  = (const float*)d_in[5];
    const float* out_b  = (const float*)d_in[6];

    char* ws = (char*)d_ws;
    unsigned short* xnT  = (unsigned short*)ws;                   // 32 MB
    unsigned short* vpr  = (unsigned short*)(ws + 33554432);      // 32 MB
    unsigned short* SP   = (unsigned short*)(ws + 67108864);      // 32 MB (half-batch E)
    unsigned short* wqkT = (unsigned short*)(ws + 100663296);     // 512 KB
    unsigned short* w2   = (unsigned short*)(ws + 101187584);     // 512 KB
    float* gvec          = (float*)(ws + 101711872);
    float* bias2         = (float*)(ws + 101713920);
    float* meanp         = (float*)(ws + 101715968);
    float* rstdp         = (float*)(ws + 101716992);
    float* tmaxp         = (float*)(ws + 101718016);              // 1 MB
    float* tsump         = (float*)(ws + 102766592);              // 1 MB
    float* ratiop        = (float*)(ws + 103815168);              // 512 KB (per half)

    unsigned short* slot0 = SP;
    unsigned short* owb   = SP + 786432;

    unsigned short* T1 = (unsigned short*)((char*)d_out + 33554432);
    float* outF = (float*)d_out;

    const float* wk_f = qkv_w + (size_t)512 * CD;

    gn_stats<<<256, 256, 0, stream>>>(x, meanp, rstdp);
    gn_norm_t<<<dim3(16, 8, 32), 256, 0, stream>>>(x, meanp, rstdp, gamma, beta, xnT);

    tpose3_bf16<<<dim3(8, 8, 3), 256, 0, stream>>>(qkv_w, slot0);
    cvt_bf16<<<256, 256, 0, stream>>>(out_w, owb);
    gvec_kernel<<<8, 256, 0, stream>>>(wk_f, qkv_b, gvec);
    bias2_kernel<<<128, 256, 0, stream>>>(out_w, qkv_b + 1024, bias2);

    // z=0: wqkT = wkT . wqT^T ; z=1: w2 = owb . wvT^T
    gemm_bt<3><<<dim3(4, 4, 2), 256, 0, stream>>>(slot0 + 524288, slot0, wqkT, nullptr,
        512, 512, 512, 262144, 262144, 262144);

    // T1[b,i,d] = xnT[b,i,:] . wqkT[d,:] + g[d]   (256^2 counted-vmcnt)
    gemm8<0><<<dim3(2, 4, 32), 512, 0, stream>>>(xnT, wqkT, T1, gvec,
        1024, 512, 512, 1024LL * 512, 0, 1024LL * 512);
    // vpr[b,o,i] = w2[o,:] . xnT[b,i,:] + bias2[o]   (256^2 counted-vmcnt)
    gemm8<1><<<dim3(4, 2, 32), 512, 0, stream>>>(w2, xnT, vpr, bias2,
        512, 1024, 512, 0, 1024LL * 512, 512LL * 1024);

    for (int h = 0; h < 2; ++h) {
        const unsigned short* T1h = T1 + (size_t)h * 16 * 1024 * 512;
        const unsigned short* xh  = xnT + (size_t)h * 16 * 1024 * 512;
        float* tmaxh = tmaxp + (size_t)h * 16 * 8 * 1024;
        float* tsumh = tsump + (size_t)h * 16 * 8 * 1024;

        scores_gemm<<<dim3(8, 8, 16), 256, 0, stream>>>(T1h, xh, SP, tmaxh, tsumh);
        rescale_kernel<<<64, 256, 0, stream>>>(tmaxh, tsumh, ratiop);
        pv_gemm<<<dim3(8, 4, 16), 256, 0, stream>>>(
            vpr + (size_t)h * 16 * 512 * 1024, SP,
            outF + (size_t)h * 16 * 512 * 1024, out_b,
            x + (size_t)h * 16 * 512 * 1024, ratiop);
    }
    (void)in_sizes; (void)n_in; (void)out_size; (void)ws_size;
}

// Round 17
// 218.502 us; speedup vs baseline: 1.2658x; 1.0098x over previous
//
#include <hip/hip_runtime.h>

#define HW 1024
#define CD 512

typedef __bf16 bf16x8 __attribute__((ext_vector_type(8)));
typedef float f32x4 __attribute__((ext_vector_type(4)));

__device__ __forceinline__ unsigned short f2bf(float f) {
    unsigned int u = __float_as_uint(f);
    u += 0x7fff + ((u >> 16) & 1);   // RNE
    return (unsigned short)(u >> 16);
}
__device__ __forceinline__ float bf2f(unsigned short h) {
    return __uint_as_float((unsigned)h << 16);
}

#define AS1(p) ((__attribute__((address_space(1))) void*)(p))
#define AS3(p) ((__attribute__((address_space(3))) void*)(p))
#define GLD16(gp, lp) __builtin_amdgcn_global_load_lds(AS1(gp), AS3(lp), 16, 0, 0)
#define WAITVM(n) do { asm volatile("s_waitcnt vmcnt(" #n ")" ::: "memory"); \
                       __builtin_amdgcn_sched_barrier(0); } while (0)

// ---------------- GroupNorm stats: one block per (b,g)
__global__ __launch_bounds__(256)
void gn_stats(const float* __restrict__ x, float* __restrict__ mean, float* __restrict__ rstd) {
    int bg = blockIdx.x;
    const float4* p4 = (const float4*)(x + (size_t)bg * 65536);
    int tid = threadIdx.x;
    float s = 0.f, ss = 0.f;
#pragma unroll 8
    for (int it = 0; it < 64; ++it) {
        float4 v = p4[tid + it * 256];
        s  += v.x + v.y + v.z + v.w;
        ss += v.x * v.x + v.y * v.y + v.z * v.z + v.w * v.w;
    }
#pragma unroll
    for (int d = 32; d > 0; d >>= 1) { s += __shfl_down(s, d); ss += __shfl_down(ss, d); }
    __shared__ float ls[4], lss[4];
    if ((tid & 63) == 0) { ls[tid >> 6] = s; lss[tid >> 6] = ss; }
    __syncthreads();
    if (tid == 0) {
        float S = ls[0] + ls[1] + ls[2] + ls[3];
        float SS = lss[0] + lss[1] + lss[2] + lss[3];
        float m = S * (1.f / 65536.f);
        float v = SS * (1.f / 65536.f) - m * m;
        mean[bg] = m;
        rstd[bg] = rsqrtf(v + 1e-5f);
    }
}

// ---------------- normalize + transpose: x[b,c,hw] f32 -> xnT[b,hw,c] bf16 (pad 67)
__global__ __launch_bounds__(256)
void gn_norm_t(const float* __restrict__ x, const float* __restrict__ mean, const float* __restrict__ rstd,
               const float* __restrict__ gamma, const float* __restrict__ beta,
               unsigned short* __restrict__ xnT) {
    __shared__ unsigned short tile[64][67];
    int i0 = blockIdx.x * 64, c0 = blockIdx.y * 64, b = blockIdx.z;
    float m = mean[b * 8 + blockIdx.y];
    float r = rstd[b * 8 + blockIdx.y];
    int tid = threadIdx.x;
    int tr = tid >> 4, tc = (tid & 15) * 4;
    const float* xb = x + ((size_t)b * CD + c0) * HW + i0;
#pragma unroll
    for (int p = 0; p < 4; ++p) {
        int c = tr + p * 16;
        float g = gamma[c0 + c] * r;
        float bb = beta[c0 + c] - m * g;
        float4 v = *(const float4*)(xb + (size_t)c * HW + tc);
        tile[c][tc + 0] = f2bf(v.x * g + bb);
        tile[c][tc + 1] = f2bf(v.y * g + bb);
        tile[c][tc + 2] = f2bf(v.z * g + bb);
        tile[c][tc + 3] = f2bf(v.w * g + bb);
    }
    __syncthreads();
    unsigned short* ob = xnT + ((size_t)b * HW + i0) * CD + c0;
#pragma unroll
    for (int p = 0; p < 4; ++p) {
        int ir = tr + p * 16;
        ushort4 u;
        u.x = tile[tc + 0][ir];
        u.y = tile[tc + 1][ir];
        u.z = tile[tc + 2][ir];
        u.w = tile[tc + 3][ir];
        *(ushort4*)(ob + (size_t)ir * CD + tc) = u;
    }
}

// ---------------- transpose + cvt x3: qkv_w row-blocks -> bf16 transposed (pad 67)
__global__ __launch_bounds__(256)
void tpose3_bf16(const float* __restrict__ qkv_w, unsigned short* __restrict__ dst0) {
    __shared__ unsigned short tile[64][67];
    const int zmap[3] = {0, 2, 1};
    const float* src = qkv_w + (size_t)blockIdx.z * CD * CD;
    unsigned short* dst = dst0 + (size_t)zmap[blockIdx.z] * CD * CD;
    int i0 = blockIdx.x * 64, c0 = blockIdx.y * 64;
    int tid = threadIdx.x;
    int tr = tid >> 4, tc = (tid & 15) * 4;
#pragma unroll
    for (int p = 0; p < 4; ++p) {
        int r = tr + p * 16;
        float4 v = *(const float4*)(src + (size_t)(i0 + r) * CD + c0 + tc);
        tile[r][tc + 0] = f2bf(v.x);
        tile[r][tc + 1] = f2bf(v.y);
        tile[r][tc + 2] = f2bf(v.z);
        tile[r][tc + 3] = f2bf(v.w);
    }
    __syncthreads();
#pragma unroll
    for (int p = 0; p < 4; ++p) {
        int ir = tr + p * 16;
        ushort4 u;
        u.x = tile[tc + 0][ir];
        u.y = tile[tc + 1][ir];
        u.z = tile[tc + 2][ir];
        u.w = tile[tc + 3][ir];
        *(ushort4*)(dst + (size_t)(c0 + ir) * CD + i0 + tc) = u;
    }
}

// ---------------- f32 -> bf16 convert
__global__ __launch_bounds__(256)
void cvt_bf16(const float* __restrict__ src, unsigned short* __restrict__ dst) {
    int i = blockIdx.x * 256 + threadIdx.x;
    float4 v = ((const float4*)src)[i];
    ushort4 u;
    u.x = f2bf(v.x); u.y = f2bf(v.y); u.z = f2bf(v.z); u.w = f2bf(v.w);
    ((ushort4*)dst)[i] = u;
}

// ---------------- g[d] = sum_o wk[o][d] * bq[o]
__global__ __launch_bounds__(256)
void gvec_kernel(const float* __restrict__ wk, const float* __restrict__ bq,
                 float* __restrict__ g) {
    __shared__ float red[4][64];
    int d = blockIdx.x * 64 + (threadIdx.x & 63);
    int os = threadIdx.x >> 6;
    float acc = 0.f;
    for (int o = os * 128; o < os * 128 + 128; ++o)
        acc += wk[(size_t)o * CD + d] * bq[o];
    red[os][threadIdx.x & 63] = acc;
    __syncthreads();
    if (threadIdx.x < 64)
        g[blockIdx.x * 64 + threadIdx.x] = red[0][threadIdx.x] + red[1][threadIdx.x] +
                                           red[2][threadIdx.x] + red[3][threadIdx.x];
}

// ---------------- bias2[o] = sum_t out_w[o][t] * bv[t]
__global__ __launch_bounds__(256)
void bias2_kernel(const float* __restrict__ out_w, const float* __restrict__ bv,
                  float* __restrict__ bias2) {
    int wid = threadIdx.x >> 6, lane = threadIdx.x & 63;
    int o = blockIdx.x * 4 + wid;
    float acc = 0.f;
#pragma unroll
    for (int t = 0; t < 512; t += 64)
        acc += out_w[(size_t)o * CD + t + lane] * bv[t + lane];
#pragma unroll
    for (int d = 32; d > 0; d >>= 1) acc += __shfl_down(acc, d);
    if (lane == 0) bias2[o] = acc;
}

// ======== gemm8: 256x256 tile, BK=64, counted-vmcnt 2-deep pipeline (validated R16) ====
template<int EPI>
__global__ __launch_bounds__(512, 2)
void gemm8(const unsigned short* __restrict__ A, const unsigned short* __restrict__ B,
           unsigned short* __restrict__ C, const float* __restrict__ bias,
           int M, int N, int K, long long sA, long long sB, long long sC) {
    unsigned nx = gridDim.x, ny = gridDim.y;
    unsigned lin = blockIdx.x + nx * (blockIdx.y + ny * blockIdx.z);
    unsigned nwg = nx * ny * gridDim.z;
    unsigned work = (lin & 7) * (nwg >> 3) + (lin >> 3);
    unsigned bx = work % nx; work /= nx;
    unsigned by = work % ny;
    unsigned bz = work / ny;

    A += (size_t)bz * sA;
    B += (size_t)bz * sB;
    int m0 = by * 256, n0 = bx * 256;

    __shared__ unsigned short lA[2][256 * 64];
    __shared__ unsigned short lB[2][256 * 64];

    int tid = threadIdx.x, lane = tid & 63, wid = tid >> 6;
    int wr = wid >> 2, wc = wid & 3;

    f32x4 acc[8][4] = {};

    int strow[4], stcol[4];
#pragma unroll
    for (int s = 0; s < 4; ++s) {
        int idx = s * 512 + tid;
        strow[s] = idx >> 3;
        stcol[s] = ((idx & 7) ^ (strow[s] & 7)) * 8;
    }

    auto stage = [&](int buf, int kt) {
        int k0 = kt << 6;
#pragma unroll
        for (int s = 0; s < 4; ++s)
            GLD16(A + (size_t)(m0 + strow[s]) * K + k0 + stcol[s], &lA[buf][(size_t)(s * 512 + tid) * 8]);
#pragma unroll
        for (int s = 0; s < 4; ++s)
            GLD16(B + (size_t)(n0 + strow[s]) * K + k0 + stcol[s], &lB[buf][(size_t)(s * 512 + tid) * 8]);
    };

    int NT = K >> 6;
    stage(0, 0);
    if (NT > 1) stage(1, 1);

    for (int t = 0; t < NT; ++t) {
        if (t < NT - 1) WAITVM(8); else WAITVM(0);
        __builtin_amdgcn_s_barrier();
        const char* pa = (const char*)lA[t & 1];
        const char* pb = (const char*)lB[t & 1];
        __builtin_amdgcn_s_setprio(1);
#pragma unroll
        for (int kk = 0; kk < 64; kk += 32) {
            int koff = (kk + (lane >> 4) * 8) * 2;
            bf16x8 af[8], bfr[4];
#pragma unroll
            for (int m = 0; m < 8; ++m) {
                int row = wr * 128 + m * 16 + (lane & 15);
                af[m] = *(const bf16x8*)(pa + ((row * 128 + koff) ^ ((row & 7) << 4)));
            }
#pragma unroll
            for (int n = 0; n < 4; ++n) {
                int row = wc * 64 + n * 16 + (lane & 15);
                bfr[n] = *(const bf16x8*)(pb + ((row * 128 + koff) ^ ((row & 7) << 4)));
            }
#pragma unroll
            for (int m = 0; m < 8; ++m)
#pragma unroll
                for (int n = 0; n < 4; ++n)
                    acc[m][n] = __builtin_amdgcn_mfma_f32_16x16x32_bf16(af[m], bfr[n], acc[m][n], 0, 0, 0);
        }
        __builtin_amdgcn_s_setprio(0);
        __builtin_amdgcn_s_barrier();
        if (t + 2 < NT) stage(t & 1, t + 2);
    }

    int rl = (lane >> 4) * 4;
    int cl = lane & 15;
    unsigned short* Cb = C + (size_t)bz * sC;
#pragma unroll
    for (int m = 0; m < 8; ++m)
#pragma unroll
        for (int n = 0; n < 4; ++n) {
            int gm = m0 + wr * 128 + m * 16 + rl;
            int gn = n0 + wc * 64 + n * 16 + cl;
#pragma unroll
            for (int rg = 0; rg < 4; ++rg) {
                float v = acc[m][n][rg];
                if (EPI == 0) v += bias[gn];
                if (EPI == 1) v += bias[gm + rg];
                Cb[(size_t)(gm + rg) * N + gn] = f2bf(v);
            }
        }
}

// ======== scores8: 256x256 counted-vmcnt GEMM + log2-softmax epilogue ================
// Stats per (row, 256-col tile): tmax/tsum indexed ((bz*4 + bx)*HW + row).
__global__ __launch_bounds__(512, 2)
void scores8(const unsigned short* __restrict__ T1, const unsigned short* __restrict__ xnT,
             unsigned short* __restrict__ S, float* __restrict__ tmax, float* __restrict__ tsum) {
    unsigned nx = gridDim.x, ny = gridDim.y;
    unsigned lin = blockIdx.x + nx * (blockIdx.y + ny * blockIdx.z);
    unsigned nwg = nx * ny * gridDim.z;
    unsigned work = (lin & 7) * (nwg >> 3) + (lin >> 3);
    unsigned bx = work % nx; work /= nx;
    unsigned by = work % ny;
    unsigned bz = work / ny;

    const unsigned short* Ab = T1 + (size_t)bz * HW * CD;
    const unsigned short* Bb = xnT + (size_t)bz * HW * CD;
    int m0 = by * 256, n0 = bx * 256;

    __shared__ unsigned short lA[2][256 * 64];
    __shared__ unsigned short lB[2][256 * 64];
    __shared__ float redm[4][256];
    __shared__ float reds[4][256];

    int tid = threadIdx.x, lane = tid & 63, wid = tid >> 6;
    int wr = wid >> 2, wc = wid & 3;

    f32x4 acc[8][4] = {};

    int strow[4], stcol[4];
#pragma unroll
    for (int s = 0; s < 4; ++s) {
        int idx = s * 512 + tid;
        strow[s] = idx >> 3;
        stcol[s] = ((idx & 7) ^ (strow[s] & 7)) * 8;
    }

    auto stage = [&](int buf, int kt) {
        int k0 = kt << 6;
#pragma unroll
        for (int s = 0; s < 4; ++s)
            GLD16(Ab + (size_t)(m0 + strow[s]) * CD + k0 + stcol[s], &lA[buf][(size_t)(s * 512 + tid) * 8]);
#pragma unroll
        for (int s = 0; s < 4; ++s)
            GLD16(Bb + (size_t)(n0 + strow[s]) * CD + k0 + stcol[s], &lB[buf][(size_t)(s * 512 + tid) * 8]);
    };

    stage(0, 0);
    stage(1, 1);

    for (int t = 0; t < 8; ++t) {
        if (t < 7) WAITVM(8); else WAITVM(0);
        __builtin_amdgcn_s_barrier();
        const char* pa = (const char*)lA[t & 1];
        const char* pb = (const char*)lB[t & 1];
        __builtin_amdgcn_s_setprio(1);
#pragma unroll
        for (int kk = 0; kk < 64; kk += 32) {
            int koff = (kk + (lane >> 4) * 8) * 2;
            bf16x8 af[8], bfr[4];
#pragma unroll
            for (int m = 0; m < 8; ++m) {
                int row = wr * 128 + m * 16 + (lane & 15);
                af[m] = *(const bf16x8*)(pa + ((row * 128 + koff) ^ ((row & 7) << 4)));
            }
#pragma unroll
            for (int n = 0; n < 4; ++n) {
                int row = wc * 64 + n * 16 + (lane & 15);
                bfr[n] = *(const bf16x8*)(pb + ((row * 128 + koff) ^ ((row & 7) << 4)));
            }
#pragma unroll
            for (int m = 0; m < 8; ++m)
#pragma unroll
                for (int n = 0; n < 4; ++n)
                    acc[m][n] = __builtin_amdgcn_mfma_f32_16x16x32_bf16(af[m], bfr[n], acc[m][n], 0, 0, 0);
        }
        __builtin_amdgcn_s_setprio(0);
        __builtin_amdgcn_s_barrier();
        if (t + 2 < 8) stage(t & 1, t + 2);
    }

    const float SL2E = 0.044194173824159216f * 1.4426950408889634f;
#pragma unroll
    for (int m = 0; m < 8; ++m)
#pragma unroll
        for (int n = 0; n < 4; ++n) acc[m][n] *= SL2E;

    int rl = (lane >> 4) * 4;
    int cl = lane & 15;

    // per-row max over this wave's 64 cols (in-lane n, then 16-lane shfl), then x4 waves via LDS
    float mr[8][4];
#pragma unroll
    for (int m = 0; m < 8; ++m)
#pragma unroll
        for (int rg = 0; rg < 4; ++rg)
            mr[m][rg] = fmaxf(fmaxf(acc[m][0][rg], acc[m][1][rg]),
                              fmaxf(acc[m][2][rg], acc[m][3][rg]));
#pragma unroll
    for (int d = 1; d < 16; d <<= 1)
#pragma unroll
        for (int m = 0; m < 8; ++m)
#pragma unroll
            for (int rg = 0; rg < 4; ++rg) mr[m][rg] = fmaxf(mr[m][rg], __shfl_xor(mr[m][rg], d));
    if ((lane & 15) == 0)
#pragma unroll
        for (int m = 0; m < 8; ++m)
#pragma unroll
            for (int rg = 0; rg < 4; ++rg) redm[wc][wr * 128 + m * 16 + rl + rg] = mr[m][rg];
    __syncthreads();
    float Mt[8][4];
#pragma unroll
    for (int m = 0; m < 8; ++m)
#pragma unroll
        for (int rg = 0; rg < 4; ++rg) {
            int row = wr * 128 + m * 16 + rl + rg;
            Mt[m][rg] = fmaxf(fmaxf(redm[0][row], redm[1][row]),
                              fmaxf(redm[2][row], redm[3][row]));
        }

    // E = exp2(t - Mt) in acc; row-sum
    float sr[8][4] = {};
#pragma unroll
    for (int m = 0; m < 8; ++m)
#pragma unroll
        for (int n = 0; n < 4; ++n)
#pragma unroll
            for (int rg = 0; rg < 4; ++rg) {
                float e = __builtin_amdgcn_exp2f(acc[m][n][rg] - Mt[m][rg]);
                acc[m][n][rg] = e;
                sr[m][rg] += e;
            }
#pragma unroll
    for (int d = 1; d < 16; d <<= 1)
#pragma unroll
        for (int m = 0; m < 8; ++m)
#pragma unroll
            for (int rg = 0; rg < 4; ++rg) sr[m][rg] += __shfl_xor(sr[m][rg], d);
    if ((lane & 15) == 0)
#pragma unroll
        for (int m = 0; m < 8; ++m)
#pragma unroll
            for (int rg = 0; rg < 4; ++rg) reds[wc][wr * 128 + m * 16 + rl + rg] = sr[m][rg];
    __syncthreads();

    if (tid < 256) {
        float M = fmaxf(fmaxf(redm[0][tid], redm[1][tid]),
                        fmaxf(redm[2][tid], redm[3][tid]));
        float Z = reds[0][tid] + reds[1][tid] + reds[2][tid] + reds[3][tid];
        size_t o = ((size_t)bz * 4 + bx) * HW + m0 + tid;
        tmax[o] = M;
        tsum[o] = Z;
    }

    unsigned short* Sb = S + (size_t)bz * HW * HW;
#pragma unroll
    for (int m = 0; m < 8; ++m)
#pragma unroll
        for (int n = 0; n < 4; ++n) {
            int gm = m0 + wr * 128 + m * 16 + rl;
            int gn = n0 + wc * 64 + n * 16 + cl;
#pragma unroll
            for (int rg = 0; rg < 4; ++rg)
                Sb[(size_t)(gm + rg) * HW + gn] = f2bf(acc[m][n][rg]);
        }
}

// ---------------- generic bf16 GEMM (128x128, 2-phase dbuf) — weight-pair GEMM
template<int EPI>
__global__ __launch_bounds__(256, 2)
void gemm_bt(const unsigned short* __restrict__ A, const unsigned short* __restrict__ B,
             void* __restrict__ Cv, const float* __restrict__ bias,
             int M, int N, int K, long long sA, long long sB, long long sC) {
    unsigned nx = gridDim.x, ny = gridDim.y;
    unsigned lin = blockIdx.x + nx * (blockIdx.y + ny * blockIdx.z);
    unsigned nwg = nx * ny * gridDim.z;
    unsigned work = (lin & 7) * (nwg >> 3) + (lin >> 3);
    unsigned bx = work % nx; work /= nx;
    unsigned by = work % ny;
    unsigned bz = work / ny;

    A += (size_t)bz * sA;
    B += (size_t)bz * sB;
    int m0 = by * 128, n0 = bx * 128;

    __shared__ unsigned short lA[2][128 * 64];
    __shared__ unsigned short lB[2][128 * 64];

    int tid = threadIdx.x;
    int lane = tid & 63;
    int wr = (tid >> 6) >> 1, wc = (tid >> 6) & 1;

    f32x4 acc[4][4] = {};

    int strow[4], stcol[4];
#pragma unroll
    for (int s = 0; s < 4; ++s) {
        int row = (s * 256 + tid) >> 3;
        int g = (tid & 7) ^ (row & 7);
        strow[s] = row;
        stcol[s] = g * 8;
    }

    auto stage = [&](int buf, int k0) {
#pragma unroll
        for (int s = 0; s < 4; ++s) {
            GLD16(A + (size_t)(m0 + strow[s]) * K + k0 + stcol[s], &lA[buf][(size_t)(s * 256 + tid) * 8]);
            GLD16(B + (size_t)(n0 + strow[s]) * K + k0 + stcol[s], &lB[buf][(size_t)(s * 256 + tid) * 8]);
        }
    };

    int NT = K >> 6;
    stage(0, 0);
    __syncthreads();
    int cur = 0;
    for (int t = 0; t < NT; ++t) {
        if (t + 1 < NT) stage(cur ^ 1, (t + 1) << 6);
        const char* pa = (const char*)lA[cur];
        const char* pb = (const char*)lB[cur];
#pragma unroll
        for (int kk = 0; kk < 64; kk += 32) {
            bf16x8 af[4], bfr[4];
#pragma unroll
            for (int m = 0; m < 4; ++m) {
                int row = wr * 64 + m * 16 + (lane & 15);
                int off = (row * 128 + (kk + (lane >> 4) * 8) * 2) ^ ((row & 7) << 4);
                af[m] = *(const bf16x8*)(pa + off);
            }
#pragma unroll
            for (int n = 0; n < 4; ++n) {
                int row = wc * 64 + n * 16 + (lane & 15);
                int off = (row * 128 + (kk + (lane >> 4) * 8) * 2) ^ ((row & 7) << 4);
                bfr[n] = *(const bf16x8*)(pb + off);
            }
#pragma unroll
            for (int m = 0; m < 4; ++m)
#pragma unroll
                for (int n = 0; n < 4; ++n)
                    acc[m][n] = __builtin_amdgcn_mfma_f32_16x16x32_bf16(af[m], bfr[n], acc[m][n], 0, 0, 0);
        }
        __syncthreads();
        cur ^= 1;
    }

    int rl = (lane >> 4) * 4;
    int cl = lane & 15;
    unsigned short* Cb = (unsigned short*)Cv + (size_t)bz * sC;
#pragma unroll
    for (int m = 0; m < 4; ++m)
#pragma unroll
        for (int n = 0; n < 4; ++n) {
            int gm = m0 + wr * 64 + m * 16 + rl;
            int gn = n0 + wc * 64 + n * 16 + cl;
#pragma unroll
            for (int rg = 0; rg < 4; ++rg) {
                float v = acc[m][n][rg];
                if (EPI == 0) v += bias[gn];
                if (EPI == 1) v += bias[gm + rg];
                Cb[(size_t)(gm + rg) * N + gn] = f2bf(v);
            }
        }
}

// ---------------- Horner ratios for PV: 4 col-tiles of 256
// r[jt][i] = exp2(Mt_jt - Mt_{jt+1}) (jt<3), r[3][i] = exp2(Mt_3 - Mrow) / Z
__global__ __launch_bounds__(256)
void rescale_kernel(const float* __restrict__ tmax, const float* __restrict__ tsum,
                    float* __restrict__ ratio) {
    int r = blockIdx.x * 256 + threadIdx.x;   // 16*1024 rows per half
    int b = r >> 10, i = r & 1023;
    const float* tm = tmax + (size_t)b * 4 * HW + i;
    const float* ts = tsum + (size_t)b * 4 * HW + i;
    float M = -1e30f;
#pragma unroll
    for (int jt = 0; jt < 4; ++jt) M = fmaxf(M, tm[(size_t)jt * HW]);
    float Z = 0.f;
#pragma unroll
    for (int jt = 0; jt < 4; ++jt) Z += ts[(size_t)jt * HW] * __builtin_amdgcn_exp2f(tm[(size_t)jt * HW] - M);
    float rZ = 1.0f / Z;
#pragma unroll
    for (int jt = 0; jt < 3; ++jt)
        ratio[((size_t)b * 4 + jt) * HW + i] =
            __builtin_amdgcn_exp2f(tm[(size_t)jt * HW] - tm[(size_t)(jt + 1) * HW]);
    ratio[((size_t)b * 4 + 3) * HW + i] = __builtin_amdgcn_exp2f(tm[(size_t)3 * HW] - M) * rZ;
}

// ---------------- PV GEMM (128^2 2-phase dbuf): Horner fold every 4th K-step (256-col tiles)
__global__ __launch_bounds__(256)
void pv_gemm(const unsigned short* __restrict__ A, const unsigned short* __restrict__ B,
             float* __restrict__ C, const float* __restrict__ bias,
             const float* __restrict__ resid, const float* __restrict__ ratio) {
    unsigned nx = gridDim.x, ny = gridDim.y;
    unsigned lin = blockIdx.x + nx * (blockIdx.y + ny * blockIdx.z);
    unsigned nwg = nx * ny * gridDim.z;
    unsigned work = (lin & 7) * (nwg >> 3) + (lin >> 3);
    unsigned bx = work % nx; work /= nx;
    unsigned by = work % ny;
    unsigned bz = work / ny;

    A += (size_t)bz * 512 * 1024;
    B += (size_t)bz * 1024 * 1024;
    int m0 = by * 128, n0 = bx * 128;

    __shared__ unsigned short lA[2][128 * 64];
    __shared__ unsigned short lB[2][128 * 64];

    int tid = threadIdx.x, lane = tid & 63;
    int wr = (tid >> 6) >> 1, wc = (tid >> 6) & 1;
    int cl = lane & 15;

    f32x4 acc[4][4] = {};

    int strow[4], stcol[4];
#pragma unroll
    for (int s = 0; s < 4; ++s) {
        int row = (s * 256 + tid) >> 3;
        int g = (tid & 7) ^ (row & 7);
        strow[s] = row;
        stcol[s] = g * 8;
    }

    auto stage = [&](int buf, int k0) {
#pragma unroll
        for (int s = 0; s < 4; ++s) {
            GLD16(A + (size_t)(m0 + strow[s]) * 1024 + k0 + stcol[s], &lA[buf][(size_t)(s * 256 + tid) * 8]);
            GLD16(B + (size_t)(n0 + strow[s]) * 1024 + k0 + stcol[s], &lB[buf][(size_t)(s * 256 + tid) * 8]);
        }
    };

    const float* rbase = ratio + (size_t)bz * 4 * HW + n0 + wc * 64 + cl;

    stage(0, 0);
    __syncthreads();
    int cur = 0;
    float r0 = 0.f, r1 = 0.f, r2 = 0.f, r3 = 0.f;
    for (int t = 0; t < 16; ++t) {
        if (t + 1 < 16) stage(cur ^ 1, (t + 1) << 6);
        if (!(t & 3)) {   // first step of a 256-col j-tile: load its ratios early
            int jt = t >> 2;
            r0 = rbase[(size_t)jt * HW + 0];
            r1 = rbase[(size_t)jt * HW + 16];
            r2 = rbase[(size_t)jt * HW + 32];
            r3 = rbase[(size_t)jt * HW + 48];
        }
        const char* pa = (const char*)lA[cur];
        const char* pb = (const char*)lB[cur];
#pragma unroll
        for (int kk = 0; kk < 64; kk += 32) {
            bf16x8 af[4], bfr[4];
#pragma unroll
            for (int m = 0; m < 4; ++m) {
                int row = wr * 64 + m * 16 + (lane & 15);
                int off = (row * 128 + (kk + (lane >> 4) * 8) * 2) ^ ((row & 7) << 4);
                af[m] = *(const bf16x8*)(pa + off);
            }
#pragma unroll
            for (int n = 0; n < 4; ++n) {
                int row = wc * 64 + n * 16 + (lane & 15);
                int off = (row * 128 + (kk + (lane >> 4) * 8) * 2) ^ ((row & 7) << 4);
                bfr[n] = *(const bf16x8*)(pb + off);
            }
#pragma unroll
            for (int m = 0; m < 4; ++m)
#pragma unroll
                for (int n = 0; n < 4; ++n)
                    acc[m][n] = __builtin_amdgcn_mfma_f32_16x16x32_bf16(af[m], bfr[n], acc[m][n], 0, 0, 0);
        }
        __syncthreads();
        cur ^= 1;
        if ((t & 3) == 3) {   // end of 256-col j-tile: Horner fold
#pragma unroll
            for (int m = 0; m < 4; ++m) {
                acc[m][0] *= r0;
                acc[m][1] *= r1;
                acc[m][2] *= r2;
                acc[m][3] *= r3;
            }
        }
    }

    int rl = (lane >> 4) * 4;
    float* Cf = C + (size_t)bz * 512 * 1024;
    const float* Rs = resid + (size_t)bz * 512 * 1024;
#pragma unroll
    for (int m = 0; m < 4; ++m)
#pragma unroll
        for (int n = 0; n < 4; ++n) {
            int gm = m0 + wr * 64 + m * 16 + rl;
            int gn = n0 + wc * 64 + n * 16 + cl;
#pragma unroll
            for (int rg = 0; rg < 4; ++rg) {
                size_t off = (size_t)(gm + rg) * 1024 + gn;
                Cf[off] = acc[m][n][rg] + bias[gm + rg] + Rs[off];
            }
        }
}

// ---------------- launch
extern "C" void kernel_launch(void* const* d_in, const int* in_sizes, int n_in,
                              void* d_out, int out_size, void* d_ws, size_t ws_size,
                              hipStream_t stream) {
    const float* x      = (const float*)d_in[0];
    const float* gamma  = (const float*)d_in[1];
    const float* beta   = (const float*)d_in[2];
    const float* qkv_w  = (const float*)d_in[3];
    const float* qkv_b  = (const float*)d_in[4];
    const float* out_w  = (const float*)d_in[5];
    const float* out_b  = (const float*)d_in[6];

    char* ws = (char*)d_ws;
    unsigned short* xnT  = (unsigned short*)ws;                   // 32 MB
    unsigned short* vpr  = (unsigned short*)(ws + 33554432);      // 32 MB
    unsigned short* SP   = (unsigned short*)(ws + 67108864);      // 32 MB (half-batch E)
    unsigned short* wqkT = (unsigned short*)(ws + 100663296);     // 512 KB
    unsigned short* w2   = (unsigned short*)(ws + 101187584);     // 512 KB
    float* gvec          = (float*)(ws + 101711872);
    float* bias2         = (float*)(ws + 101713920);
    float* meanp         = (float*)(ws + 101715968);
    float* rstdp         = (float*)(ws + 101716992);
    float* tmaxp         = (float*)(ws + 101718016);              // 512 KB (16b x 4 x 1024 x2 halves)
    float* tsump         = (float*)(ws + 102766592);              // 512 KB
    float* ratiop        = (float*)(ws + 103815168);              // 256 KB (per half)

    unsigned short* slot0 = SP;
    unsigned short* owb   = SP + 786432;

    unsigned short* T1 = (unsigned short*)((char*)d_out + 33554432);
    float* outF = (float*)d_out;

    const float* wk_f = qkv_w + (size_t)512 * CD;

    gn_stats<<<256, 256, 0, stream>>>(x, meanp, rstdp);
    gn_norm_t<<<dim3(16, 8, 32), 256, 0, stream>>>(x, meanp, rstdp, gamma, beta, xnT);

    tpose3_bf16<<<dim3(8, 8, 3), 256, 0, stream>>>(qkv_w, slot0);
    cvt_bf16<<<256, 256, 0, stream>>>(out_w, owb);
    gvec_kernel<<<8, 256, 0, stream>>>(wk_f, qkv_b, gvec);
    bias2_kernel<<<128, 256, 0, stream>>>(out_w, qkv_b + 1024, bias2);

    // z=0: wqkT = wkT . wqT^T ; z=1: w2 = owb . wvT^T
    gemm_bt<3><<<dim3(4, 4, 2), 256, 0, stream>>>(slot0 + 524288, slot0, wqkT, nullptr,
        512, 512, 512, 262144, 262144, 262144);

    // T1[b,i,d] = xnT[b,i,:] . wqkT[d,:] + g[d]   (256^2 counted-vmcnt)
    gemm8<0><<<dim3(2, 4, 32), 512, 0, stream>>>(xnT, wqkT, T1, gvec,
        1024, 512, 512, 1024LL * 512, 0, 1024LL * 512);
    // vpr[b,o,i] = w2[o,:] . xnT[b,i,:] + bias2[o]   (256^2 counted-vmcnt)
    gemm8<1><<<dim3(4, 2, 32), 512, 0, stream>>>(w2, xnT, vpr, bias2,
        512, 1024, 512, 0, 1024LL * 512, 512LL * 1024);

    for (int h = 0; h < 2; ++h) {
        const unsigned short* T1h = T1 + (size_t)h * 16 * 1024 * 512;
        const unsigned short* xh  = xnT + (size_t)h * 16 * 1024 * 512;
        float* tmaxh = tmaxp + (size_t)h * 16 * 4 * 1024;
        float* tsumh = tsump + (size_t)h * 16 * 4 * 1024;

        scores8<<<dim3(4, 4, 16), 512, 0, stream>>>(T1h, xh, SP, tmaxh, tsumh);
        rescale_kernel<<<64, 256, 0, stream>>>(tmaxh, tsumh, ratiop);
        pv_gemm<<<dim3(8, 4, 16), 256, 0, stream>>>(
            vpr + (size_t)h * 16 * 512 * 1024, SP,
            outF + (size_t)h * 16 * 512 * 1024, out_b,
            x + (size_t)h * 16 * 512 * 1024, ratiop);
    }
    (void)in_sizes; (void)n_in; (void)out_size; (void)ws_size;
}